// Round 3
// baseline (242.050 us; speedup 1.0000x reference)
//
#include <hip/hip_runtime.h>
#include <hip/hip_bf16.h>

typedef __hip_bfloat16 bf16;
typedef __attribute__((ext_vector_type(8))) short short8;   // 8 bf16 = one MFMA A/B frag
typedef __attribute__((ext_vector_type(4))) float f32x4;    // MFMA C/D frag

#define MFMA(a, b, c) __builtin_amdgcn_mfma_f32_16x16x32_bf16(a, b, c, 0, 0, 0)

static __device__ __forceinline__ float b2f(unsigned short u) {
  union { unsigned u; float f; } t; t.u = ((unsigned)u) << 16; return t.f;
}
static __device__ __forceinline__ unsigned short f2bf(float f) {
  union { float f; unsigned u; } t; t.f = f;
  unsigned r = t.u + 0x7fffu + ((t.u >> 16) & 1u);   // RNE
  return (unsigned short)(r >> 16);
}
static __device__ __forceinline__ unsigned pack2(float a, float b) {
  return (unsigned)f2bf(a) | ((unsigned)f2bf(b) << 16);
}
// packed f32x2 -> bf16x2 (RNE); lo -> low 16 bits.
static __device__ __forceinline__ unsigned pack_bf2(float lo, float hi) {
  __hip_bfloat162 h = __float22bfloat162_rn(float2{lo, hi});
  union { __hip_bfloat162 h; unsigned u; } c; c.h = h; return c.u;
}

// ---- workspace layout (bf16 element offsets). d_ws is 256 MiB (harness
// fillBuffer shows 256 MiB zeroed per iter); we use ~40.6 MB. ----
#define KB_OFF   ((size_t)0)          // K  [2048][1024]
#define QB_OFF   ((size_t)2097152)    // Q  [2048][1024]
#define G1_OFF   ((size_t)4194304)    // G1 [2048][1024]
#define G2_OFF   ((size_t)6291456)    // G2 [2048][1024]
#define VT_OFF   ((size_t)8388608)    // V^T [512][2048]
#define WT_BASE  ((size_t)9437184)
#define WTK_OFF  (WT_BASE)                       // [1024][512]
#define WTQ_OFF  (WT_BASE + (size_t)524288)
#define WTG1_OFF (WT_BASE + (size_t)1048576)
#define WTG2_OFF (WT_BASE + (size_t)1572864)
#define WTV_OFF  (WT_BASE + (size_t)2097152)     // [512][512]
// attention partials (f32), above the 23.6MB legacy region:
#define NUMF_OFF ((size_t)11796480)              // f32 [4][2048][512]
#define DENF_OFF ((size_t)20185088)              // f32 [4][8][2048]
#define VSUMF_OFF ((size_t)20316160)             // f32 [512]
// end: elem 20,317,184 = 40.6 MB used

// LDS XOR swizzles (byte-address based, applied identically on write & read)
#define KSWZ(r, cB) ((((r) * 256) + (cB)) ^ ((((r) & 7)) << 4))   // [64][128] bf16 tiles
#define PSWZ(r, cB) ((((r) * 128) + (cB)) ^ ((((r) & 7)) << 4))   // [16][64] bf16 tile

// Transpose + convert W[k][n] fp32 -> Wt[n][k] bf16, all 5 weights in one launch.
__global__ __launch_bounds__(256)
void wtrans_kernel(const float* __restrict__ WK, const float* __restrict__ WQ,
                   const float* __restrict__ WG1, const float* __restrict__ WG2,
                   const float* __restrict__ WV, bf16* __restrict__ ws)
{
  __shared__ float T[32][33];
  const float* W; unsigned short* Wt; int N;
  switch (blockIdx.z) {
    case 0:  W = WK;  Wt = (unsigned short*)(ws + WTK_OFF);  N = 1024; break;
    case 1:  W = WQ;  Wt = (unsigned short*)(ws + WTQ_OFF);  N = 1024; break;
    case 2:  W = WG1; Wt = (unsigned short*)(ws + WTG1_OFF); N = 1024; break;
    case 3:  W = WG2; Wt = (unsigned short*)(ws + WTG2_OFF); N = 1024; break;
    default: W = WV;  Wt = (unsigned short*)(ws + WTV_OFF);  N = 512;  break;
  }
  int n0 = blockIdx.x * 32, k0 = blockIdx.y * 32;
  if (n0 >= N) return;
  int tid = threadIdx.x;
  int kk = tid >> 3, nn = (tid & 7) * 4;
  float4 v = *(const float4*)(W + (size_t)(k0 + kk) * N + n0 + nn);
  T[kk][nn] = v.x; T[kk][nn + 1] = v.y; T[kk][nn + 2] = v.z; T[kk][nn + 3] = v.w;
  __syncthreads();
  int n2 = tid >> 3, k2 = (tid & 7) * 4;
  uint2 pw;
  pw.x = pack2(T[k2][n2],     T[k2 + 1][n2]);
  pw.y = pack2(T[k2 + 2][n2], T[k2 + 3][n2]);
  *(uint2*)(Wt + (size_t)(n0 + n2) * 512 + k0 + k2) = pw;
}

// Batched MFMA projection GEMM (verified round 4).
__global__ __launch_bounds__(256)
void proj_mfma_kernel(const float* __restrict__ fa, const float* __restrict__ fp,
                      const float* __restrict__ sa, const float* __restrict__ sp,
                      const float* __restrict__ bKp, const float* __restrict__ bQp,
                      const float* __restrict__ bG1p, const float* __restrict__ bG2p,
                      const float* __restrict__ bVp, bf16* __restrict__ ws)
{
  __shared__ short Xs[128][40];
  __shared__ short Wsh[128][40];
  const float* X; const unsigned short* Wt; const float* bias; unsigned short* C;
  int N; bool trans = false;
  switch (blockIdx.z) {
    case 0:  X = fa; Wt = (const unsigned short*)(ws + WTK_OFF);  bias = bKp;  C = (unsigned short*)(ws + KB_OFF); N = 1024; break;
    case 1:  X = sa; Wt = (const unsigned short*)(ws + WTQ_OFF);  bias = bQp;  C = (unsigned short*)(ws + QB_OFF); N = 1024; break;
    case 2:  X = fp; Wt = (const unsigned short*)(ws + WTG1_OFF); bias = bG1p; C = (unsigned short*)(ws + G1_OFF); N = 1024; break;
    case 3:  X = sp; Wt = (const unsigned short*)(ws + WTG2_OFF); bias = bG2p; C = (unsigned short*)(ws + G2_OFF); N = 1024; break;
    default: X = fa; Wt = (const unsigned short*)(ws + WTV_OFF);  bias = bVp;  C = (unsigned short*)(ws + VT_OFF); N = 512; trans = true; break;
  }
  const int n0 = blockIdx.x * 128;
  if (n0 >= N) return;
  const int m0 = blockIdx.y * 128;
  const int tid = threadIdx.x;
  const int w = tid >> 6, l = tid & 63, l15 = l & 15, l4 = l >> 4;
  const int wm = (w & 1) * 64, wn = (w >> 1) * 64;
  const int srow = tid >> 1, shalf = (tid & 1) * 16;

  const float* xp = X + (size_t)(m0 + srow) * 512 + shalf;
  const unsigned short* wp = Wt + (size_t)(n0 + srow) * 512 + shalf;

  const f32x4 zero = {0.f, 0.f, 0.f, 0.f};
  f32x4 acc[4][4];
#pragma unroll
  for (int i = 0; i < 4; ++i)
#pragma unroll
    for (int j = 0; j < 4; ++j) acc[i][j] = zero;

  float4 px[4]; uint4 pw0, pw1;
  auto ldg = [&](int kc) {
    px[0] = *(const float4*)(xp + kc);
    px[1] = *(const float4*)(xp + kc + 4);
    px[2] = *(const float4*)(xp + kc + 8);
    px[3] = *(const float4*)(xp + kc + 12);
    pw0 = *(const uint4*)(wp + kc);
    pw1 = *(const uint4*)(wp + kc + 8);
  };
  ldg(0);

  for (int kc = 0; kc < 512; kc += 32) {
    __syncthreads();
    uint4 xa, xb;
    xa.x = pack2(px[0].x, px[0].y); xa.y = pack2(px[0].z, px[0].w);
    xa.z = pack2(px[1].x, px[1].y); xa.w = pack2(px[1].z, px[1].w);
    xb.x = pack2(px[2].x, px[2].y); xb.y = pack2(px[2].z, px[2].w);
    xb.z = pack2(px[3].x, px[3].y); xb.w = pack2(px[3].z, px[3].w);
    *(uint4*)&Xs[srow][shalf]      = xa;
    *(uint4*)&Xs[srow][shalf + 8]  = xb;
    *(uint4*)&Wsh[srow][shalf]     = pw0;
    *(uint4*)&Wsh[srow][shalf + 8] = pw1;
    __syncthreads();
    if (kc + 32 < 512) ldg(kc + 32);

    short8 xf[4], wf[4];
#pragma unroll
    for (int t = 0; t < 4; ++t) {
      xf[t] = *(const short8*)&Xs[wm + t * 16 + l15][l4 * 8];
      wf[t] = *(const short8*)&Wsh[wn + t * 16 + l15][l4 * 8];
    }
    if (!trans) {
#pragma unroll
      for (int i = 0; i < 4; ++i)
#pragma unroll
        for (int j = 0; j < 4; ++j)
          acc[i][j] = MFMA(wf[i], xf[j], acc[i][j]);   // D[n][m]
    } else {
#pragma unroll
      for (int i = 0; i < 4; ++i)
#pragma unroll
        for (int j = 0; j < 4; ++j)
          acc[i][j] = MFMA(xf[i], wf[j], acc[i][j]);   // D[m][n]
    }
  }

  if (!trans) {
#pragma unroll
    for (int tn = 0; tn < 4; ++tn) {
      float4 b4 = *(const float4*)(bias + n0 + wn + tn * 16 + l4 * 4);
#pragma unroll
      for (int tm = 0; tm < 4; ++tm) {
        uint2 pw;
        pw.x = pack2(acc[tn][tm][0] + b4.x, acc[tn][tm][1] + b4.y);
        pw.y = pack2(acc[tn][tm][2] + b4.z, acc[tn][tm][3] + b4.w);
        *(uint2*)(C + (size_t)(m0 + wm + tm * 16 + l15) * N + n0 + wn + tn * 16 + l4 * 4) = pw;
      }
    }
  } else {
#pragma unroll
    for (int tn = 0; tn < 4; ++tn) {
      float bn = bias[n0 + wn + tn * 16 + l15];
#pragma unroll
      for (int tm = 0; tm < 4; ++tm) {
        uint2 pw;
        pw.x = pack2(acc[tm][tn][0] + bn, acc[tm][tn][1] + bn);
        pw.y = pack2(acc[tm][tn][2] + bn, acc[tm][tn][3] + bn);
        *(uint2*)(C + (size_t)(n0 + wn + tn * 16 + l15) * 2048 + m0 + wm + tm * 16 + l4 * 4) = pw;
      }
    }
  }
}

// Column sums of V (= row sums of V^T [512][2048]) in f32. One wave per row.
__global__ __launch_bounds__(256)
void vsum_kernel(const bf16* __restrict__ Vtg, float* __restrict__ vs)
{
  const int row = blockIdx.x * 4 + (threadIdx.x >> 6);
  const int l = threadIdx.x & 63;
  const bf16* p = Vtg + (size_t)row * 2048 + l * 8;
  float s = 0.f;
#pragma unroll
  for (int c = 0; c < 4; ++c) {
    short8 v = *(const short8*)(p + c * 512);
#pragma unroll
    for (int j = 0; j < 8; ++j) s += b2f((unsigned short)v[j]);
  }
#pragma unroll
  for (int off = 32; off; off >>= 1) s += __shfl_xor(s, off, 64);
  if (l == 0) vs[row] = s;
}

// MFMA fused attention, n-split=4 for occupancy.
//  - 1024 blocks = 4 blocks/CU = 4 waves/SIMD (was 2; kernel is latency-bound,
//    all pipes <22%). LDS cut to 40960 B so 4 blocks fit exactly (4x40960=160KiB).
//  - V tile no longer LDS-staged: per-wave register frags loaded right after the
//    barrier (V is XCD-L2-resident; ~700cy of score MFMAs cover the latency).
//  - Denominator via per-lane f32 sum + 2 shfl_xor (lane owns one m-row thanks to
//    swapped-operand scores) - drops the ones-MFMA, improves den precision.
//  - NUM partials f32 [4][2048][512] high in the 256MiB workspace.
//  - XCD remap: each XCD owns ONE head (4 splits x 32 m-tiles): ~2.25MB <= L2.
__global__ __launch_bounds__(256, 4)
void attn_mfma_kernel(const bf16* __restrict__ Kb, const bf16* __restrict__ G1b,
                      const bf16* __restrict__ Vtg, const bf16* __restrict__ Qb,
                      const bf16* __restrict__ G2b, bf16* __restrict__ ws)
{
  __shared__ short Ks[64][128];
  __shared__ short G1s[64][128];
  __shared__ short Ps[4][16][64];

  const int tid = threadIdx.x;
  const int w   = tid >> 6;
  const int l   = tid & 63;
  const int l15 = l & 15;
  const int l4  = l >> 4;

  // XCD-aware remap: grid (32,8,4) -> flat f in [0,1024); hw round-robins f%8
  // across XCDs. vid = (f&7)*128 + (f>>3): XCD x gets vids [128x,128x+128) =
  // grps [4x,4x+4) = head x, splits 0..3, all 32 m-tiles.
  const int f = blockIdx.x + blockIdx.y * 32 + blockIdx.z * 256;
  const int vid = (f & 7) * 128 + (f >> 3);
  const int m0    = (vid & 31) * 64;
  const int grp   = vid >> 5;     // 0..31
  const int h     = grp >> 2;
  const int split = grp & 3;

  short8 qf[4], gf[4];
  {
    const size_t ro = (size_t)(m0 + w * 16 + l15) * 1024 + h * 128 + l4 * 8;
#pragma unroll
    for (int kk = 0; kk < 4; ++kk) {
      qf[kk] = *(const short8*)(Qb + ro + kk * 32);
      gf[kk] = *(const short8*)(G2b + ro + kk * 32);
    }
  }
  float sc;
  {
    float sq = 0.f, sg = 0.f;
#pragma unroll
    for (int kk = 0; kk < 4; ++kk)
#pragma unroll
      for (int j = 0; j < 8; ++j) {
        float q = b2f((unsigned short)qf[kk][j]);
        float g = b2f((unsigned short)gf[kk][j]);
        sq += q * q; sg += g * g;
      }
    sq += __shfl_xor(sq, 16, 64); sq += __shfl_xor(sq, 32, 64);
    sg += __shfl_xor(sg, 16, 64); sg += __shfl_xor(sg, 32, 64);
    // per-lane scale for row m = w*16 + l15
    sc = rsqrtf(sq) * rsqrtf(sg) * (1.0f / 16384.0f);
  }

  const int r0  = tid >> 3;
  const int c0  = (tid & 7) * 16;    // shorts
  const int c0b = c0 * 2;            // bytes

  short8 pk[4], pg[4];
  auto load_tile = [&](int nt) {     // nt in global 64-units
    const int n0 = nt * 64;
    const bf16* kp = Kb  + (size_t)(n0 + r0) * 1024 + h * 128 + c0;
    const bf16* gp = G1b + (size_t)(n0 + r0) * 1024 + h * 128 + c0;
    pk[0] = *(const short8*)(kp);
    pk[1] = *(const short8*)(kp + 8);
    pk[2] = *(const short8*)(kp + 32 * 1024);
    pk[3] = *(const short8*)(kp + 32 * 1024 + 8);
    pg[0] = *(const short8*)(gp);
    pg[1] = *(const short8*)(gp + 8);
    pg[2] = *(const short8*)(gp + 32 * 1024);
    pg[3] = *(const short8*)(gp + 32 * 1024 + 8);
  };
  const int ntbase = split * 8;
  load_tile(ntbase);

  const f32x4 zero = {0.f, 0.f, 0.f, 0.f};
  f32x4 accO[4];
#pragma unroll
  for (int t = 0; t < 4; ++t) accO[t] = zero;
  float dacc = 0.f;

  char* const ksb = (char*)&Ks[0][0];
  char* const g1p = (char*)&G1s[0][0];
  char* const psb = (char*)&Ps[w][0][0];
  const bf16* const vrow = Vtg + (size_t)(h * 64 + l15) * 2048 + l4 * 8;

  for (int nt = 0; nt < 8; ++nt) {
    __syncthreads();
    *(short8*)(ksb + KSWZ(r0,      c0b))      = pk[0];
    *(short8*)(ksb + KSWZ(r0,      c0b + 16)) = pk[1];
    *(short8*)(ksb + KSWZ(r0 + 32, c0b))      = pk[2];
    *(short8*)(ksb + KSWZ(r0 + 32, c0b + 16)) = pk[3];
    *(short8*)(g1p + KSWZ(r0,      c0b))      = pg[0];
    *(short8*)(g1p + KSWZ(r0,      c0b + 16)) = pg[1];
    *(short8*)(g1p + KSWZ(r0 + 32, c0b))      = pg[2];
    *(short8*)(g1p + KSWZ(r0 + 32, c0b + 16)) = pg[3];
    __syncthreads();

    const int n0g = (ntbase + nt) * 64;

    // issue this tile's ks=0 V frags early (L2-resident; covered by scores)
    short8 vf[4];
#pragma unroll
    for (int jt = 0; jt < 4; ++jt)
      vf[jt] = *(const short8*)(vrow + (size_t)jt * 16 * 2048 + n0g);

    if (nt + 1 < 8) load_tile(ntbase + nt + 1);

    // scores for this tile: swapped operands -> lane holds S[n-quads][m=l15]
#pragma unroll
    for (int t = 0; t < 4; ++t) {
      f32x4 sa = zero, sg2 = zero;
      __builtin_amdgcn_s_setprio(1);
#pragma unroll
      for (int kk = 0; kk < 4; ++kk) {
        short8 kbf = *(const short8*)(ksb + KSWZ(t * 16 + l15, kk * 64 + l4 * 16));
        sa  = MFMA(kbf, qf[kk], sa);
        short8 gbf = *(const short8*)(g1p + KSWZ(t * 16 + l15, kk * 64 + l4 * 16));
        sg2 = MFMA(gbf, gf[kk], sg2);
      }
      __builtin_amdgcn_s_setprio(0);
      // P' = exp(x)-1 ~= x + x^2/2 (|x| ~ 1e-4)
      float x0 = sa[0] * sg2[0] * sc;
      float x1 = sa[1] * sg2[1] * sc;
      float x2 = sa[2] * sg2[2] * sc;
      float x3 = sa[3] * sg2[3] * sc;
      float p0 = __builtin_fmaf(0.5f * x0, x0, x0);
      float p1 = __builtin_fmaf(0.5f * x1, x1, x1);
      float p2 = __builtin_fmaf(0.5f * x2, x2, x2);
      float p3 = __builtin_fmaf(0.5f * x3, x3, x3);
      dacc += (p0 + p1) + (p2 + p3);      // denominator partial (this lane's m-row)
      uint2 pw;
      pw.x = pack_bf2(p0, p1);
      pw.y = pack_bf2(p2, p3);
      // Ps[m=l15][n = t*16 + l4*4 .. +3]
      *(uint2*)(psb + PSWZ(l15, t * 32 + l4 * 8)) = pw;
    }

    // PV: ks=0 with preloaded vf, then reload vf for ks=1
    {
      short8 pf = *(const short8*)(psb + PSWZ(l15, l4 * 16));
      __builtin_amdgcn_s_setprio(1);
#pragma unroll
      for (int jt = 0; jt < 4; ++jt) accO[jt] = MFMA(pf, vf[jt], accO[jt]);
      __builtin_amdgcn_s_setprio(0);
    }
#pragma unroll
    for (int jt = 0; jt < 4; ++jt)
      vf[jt] = *(const short8*)(vrow + (size_t)jt * 16 * 2048 + n0g + 32);
    {
      short8 pf = *(const short8*)(psb + PSWZ(l15, 64 + l4 * 16));
      __builtin_amdgcn_s_setprio(1);
#pragma unroll
      for (int jt = 0; jt < 4; ++jt) accO[jt] = MFMA(pf, vf[jt], accO[jt]);
      __builtin_amdgcn_s_setprio(0);
    }
  }

  // denominator: sum this lane's m-row partial across its l4 group
  dacc += __shfl_xor(dacc, 16, 64);
  dacc += __shfl_xor(dacc, 32, 64);

  // ---- write partials (f32) ----
  float* numf = (float*)(ws + NUMF_OFF) + ((size_t)split << 20);
  float* denf = (float*)(ws + DENF_OFF);
  if (l4 == 0)
    denf[(size_t)(split * 8 + h) * 2048 + m0 + w * 16 + l15] = dacc;
#pragma unroll
  for (int jt = 0; jt < 4; ++jt) {
#pragma unroll
    for (int r = 0; r < 4; ++r)
      numf[(size_t)(m0 + w * 16 + l4 * 4 + r) * 512 + h * 64 + jt * 16 + l15]
        = accO[jt][r];
  }
}

// out[m][c] = (num0..3 + Vsum[c]) / (2048 + den0..3), 8 elems/thread
__global__ __launch_bounds__(256)
void combine_kernel(const bf16* __restrict__ ws, float* __restrict__ out)
{
  const float* numf = (const float*)(ws + NUMF_OFF);
  const float* denf = (const float*)(ws + DENF_OFF);
  const float* vsum = (const float*)(ws + VSUMF_OFF);
  int idx = (blockIdx.x * 256 + threadIdx.x) * 8;
  int m = idx >> 9, c = idx & 511, h = c >> 6;
  float d = 2048.0f;
#pragma unroll
  for (int s = 0; s < 4; ++s) d += denf[(size_t)(s * 8 + h) * 2048 + m];
  float rd = 1.0f / d;
  float4 a0 = *(const float4*)(vsum + c);
  float4 a1 = *(const float4*)(vsum + c + 4);
#pragma unroll
  for (int s = 0; s < 4; ++s) {
    float4 n0 = *(const float4*)(numf + ((size_t)s << 20) + idx);
    float4 n1 = *(const float4*)(numf + ((size_t)s << 20) + idx + 4);
    a0.x += n0.x; a0.y += n0.y; a0.z += n0.z; a0.w += n0.w;
    a1.x += n1.x; a1.y += n1.y; a1.z += n1.z; a1.w += n1.w;
  }
  *(float4*)(out + idx)     = float4{a0.x * rd, a0.y * rd, a0.z * rd, a0.w * rd};
  *(float4*)(out + idx + 4) = float4{a1.x * rd, a1.y * rd, a1.z * rd, a1.w * rd};
}

extern "C" void kernel_launch(void* const* d_in, const int* in_sizes, int n_in,
                              void* d_out, int out_size, void* d_ws, size_t ws_size,
                              hipStream_t stream) {
  const float* first_app  = (const float*)d_in[0];
  const float* first_pos  = (const float*)d_in[1];
  const float* second_app = (const float*)d_in[2];
  const float* second_pos = (const float*)d_in[3];
  const float* WK  = (const float*)d_in[4];
  const float* bK  = (const float*)d_in[5];
  const float* WQ  = (const float*)d_in[6];
  const float* bQ  = (const float*)d_in[7];
  const float* WV  = (const float*)d_in[8];
  const float* bV  = (const float*)d_in[9];
  const float* WG1 = (const float*)d_in[10];
  const float* bG1 = (const float*)d_in[11];
  const float* WG2 = (const float*)d_in[12];
  const float* bG2 = (const float*)d_in[13];

  bf16* ws = (bf16*)d_ws;

  wtrans_kernel<<<dim3(32, 16, 5), 256, 0, stream>>>(WK, WQ, WG1, WG2, WV, ws);
  proj_mfma_kernel<<<dim3(8, 16, 5), 256, 0, stream>>>(
      first_app, first_pos, second_app, second_pos, bK, bQ, bG1, bG2, bV, ws);
  vsum_kernel<<<dim3(128), 256, 0, stream>>>(ws + VT_OFF, (float*)(ws + VSUMF_OFF));
  attn_mfma_kernel<<<dim3(32, 8, 4), 256, 0, stream>>>(
      ws + KB_OFF, ws + G1_OFF, ws + VT_OFF, ws + QB_OFF, ws + G2_OFF, ws);
  combine_kernel<<<dim3(512), 256, 0, stream>>>(ws, (float*)d_out);
}

// Round 4
// 188.000 us; speedup vs baseline: 1.2875x; 1.2875x over previous
//
#include <hip/hip_runtime.h>
#include <hip/hip_bf16.h>

typedef __hip_bfloat16 bf16;
typedef __attribute__((ext_vector_type(8))) short short8;   // 8 bf16 = one MFMA A/B frag
typedef __attribute__((ext_vector_type(4))) float f32x4;    // MFMA C/D frag

#define MFMA(a, b, c) __builtin_amdgcn_mfma_f32_16x16x32_bf16(a, b, c, 0, 0, 0)

static __device__ __forceinline__ float b2f(unsigned short u) {
  union { unsigned u; float f; } t; t.u = ((unsigned)u) << 16; return t.f;
}
static __device__ __forceinline__ unsigned short f2bf(float f) {
  union { float f; unsigned u; } t; t.f = f;
  unsigned r = t.u + 0x7fffu + ((t.u >> 16) & 1u);   // RNE
  return (unsigned short)(r >> 16);
}
static __device__ __forceinline__ unsigned pack2(float a, float b) {
  return (unsigned)f2bf(a) | ((unsigned)f2bf(b) << 16);
}
// packed f32x2 -> bf16x2 (RNE); lo -> low 16 bits.
static __device__ __forceinline__ unsigned pack_bf2(float lo, float hi) {
  __hip_bfloat162 h = __float22bfloat162_rn(float2{lo, hi});
  union { __hip_bfloat162 h; unsigned u; } c; c.h = h; return c.u;
}

// ---- workspace layout (bf16 element offsets) ----
#define KB_OFF   ((size_t)0)          // K  [2048][1024]
#define QB_OFF   ((size_t)2097152)    // Q  [2048][1024]
#define G1_OFF   ((size_t)4194304)    // G1 [2048][1024]
#define G2_OFF   ((size_t)6291456)    // G2 [2048][1024]
#define VT_OFF   ((size_t)8388608)    // V^T [512][2048]
#define WT_BASE  ((size_t)9437184)
#define WTK_OFF  (WT_BASE)                       // [1024][512]
#define WTQ_OFF  (WT_BASE + (size_t)524288)
#define WTG1_OFF (WT_BASE + (size_t)1048576)
#define WTG2_OFF (WT_BASE + (size_t)1572864)
#define WTV_OFF  (WT_BASE + (size_t)2097152)     // [512][512]
// After proj, the WT region is dead -> reuse for attention partials:
#define NUM0_OFF (WT_BASE)                       // bf16 [2048][512] (n-split 0)
#define NUM1_OFF (WT_BASE + (size_t)1048576)     // bf16 [2048][512] (n-split 1)
#define DEN_OFF  (WT_BASE + (size_t)2097152)     // f32  [2][8][2048] (as raw bytes)
#define VSUM_OFF (DEN_OFF + (size_t)65536)       // f32  [512] column sums of V

// LDS XOR swizzles (byte-address based, applied identically on write & read)
#define KSWZ(r, cB) ((((r) * 256) + (cB)) ^ ((((r) & 7)) << 4))   // [64][128] bf16 tiles
#define PSWZ(r, cB) ((((r) * 128) + (cB)) ^ ((((r) & 7)) << 4))   // [64][64] bf16 tile
#define VSWZ(r, cB) ((((r) * 128) + (cB)) ^ ((((r) & 7)) << 4))   // [64][64] bf16 tile

// Transpose + convert W[k][n] fp32 -> Wt[n][k] bf16, all 5 weights in one launch.
__global__ __launch_bounds__(256)
void wtrans_kernel(const float* __restrict__ WK, const float* __restrict__ WQ,
                   const float* __restrict__ WG1, const float* __restrict__ WG2,
                   const float* __restrict__ WV, bf16* __restrict__ ws)
{
  __shared__ float T[32][33];
  const float* W; unsigned short* Wt; int N;
  switch (blockIdx.z) {
    case 0:  W = WK;  Wt = (unsigned short*)(ws + WTK_OFF);  N = 1024; break;
    case 1:  W = WQ;  Wt = (unsigned short*)(ws + WTQ_OFF);  N = 1024; break;
    case 2:  W = WG1; Wt = (unsigned short*)(ws + WTG1_OFF); N = 1024; break;
    case 3:  W = WG2; Wt = (unsigned short*)(ws + WTG2_OFF); N = 1024; break;
    default: W = WV;  Wt = (unsigned short*)(ws + WTV_OFF);  N = 512;  break;
  }
  int n0 = blockIdx.x * 32, k0 = blockIdx.y * 32;
  if (n0 >= N) return;
  int tid = threadIdx.x;
  int kk = tid >> 3, nn = (tid & 7) * 4;
  float4 v = *(const float4*)(W + (size_t)(k0 + kk) * N + n0 + nn);
  T[kk][nn] = v.x; T[kk][nn + 1] = v.y; T[kk][nn + 2] = v.z; T[kk][nn + 3] = v.w;
  __syncthreads();
  int n2 = tid >> 3, k2 = (tid & 7) * 4;
  uint2 pw;
  pw.x = pack2(T[k2][n2],     T[k2 + 1][n2]);
  pw.y = pack2(T[k2 + 2][n2], T[k2 + 3][n2]);
  *(uint2*)(Wt + (size_t)(n0 + n2) * 512 + k0 + k2) = pw;
}

// Batched MFMA projection GEMM (verified round 4).
__global__ __launch_bounds__(256)
void proj_mfma_kernel(const float* __restrict__ fa, const float* __restrict__ fp,
                      const float* __restrict__ sa, const float* __restrict__ sp,
                      const float* __restrict__ bKp, const float* __restrict__ bQp,
                      const float* __restrict__ bG1p, const float* __restrict__ bG2p,
                      const float* __restrict__ bVp, bf16* __restrict__ ws)
{
  __shared__ short Xs[128][40];
  __shared__ short Wsh[128][40];
  const float* X; const unsigned short* Wt; const float* bias; unsigned short* C;
  int N; bool trans = false;
  switch (blockIdx.z) {
    case 0:  X = fa; Wt = (const unsigned short*)(ws + WTK_OFF);  bias = bKp;  C = (unsigned short*)(ws + KB_OFF); N = 1024; break;
    case 1:  X = sa; Wt = (const unsigned short*)(ws + WTQ_OFF);  bias = bQp;  C = (unsigned short*)(ws + QB_OFF); N = 1024; break;
    case 2:  X = fp; Wt = (const unsigned short*)(ws + WTG1_OFF); bias = bG1p; C = (unsigned short*)(ws + G1_OFF); N = 1024; break;
    case 3:  X = sp; Wt = (const unsigned short*)(ws + WTG2_OFF); bias = bG2p; C = (unsigned short*)(ws + G2_OFF); N = 1024; break;
    default: X = fa; Wt = (const unsigned short*)(ws + WTV_OFF);  bias = bVp;  C = (unsigned short*)(ws + VT_OFF); N = 512; trans = true; break;
  }
  const int n0 = blockIdx.x * 128;
  if (n0 >= N) return;
  const int m0 = blockIdx.y * 128;
  const int tid = threadIdx.x;
  const int w = tid >> 6, l = tid & 63, l15 = l & 15, l4 = l >> 4;
  const int wm = (w & 1) * 64, wn = (w >> 1) * 64;
  const int srow = tid >> 1, shalf = (tid & 1) * 16;

  const float* xp = X + (size_t)(m0 + srow) * 512 + shalf;
  const unsigned short* wp = Wt + (size_t)(n0 + srow) * 512 + shalf;

  const f32x4 zero = {0.f, 0.f, 0.f, 0.f};
  f32x4 acc[4][4];
#pragma unroll
  for (int i = 0; i < 4; ++i)
#pragma unroll
    for (int j = 0; j < 4; ++j) acc[i][j] = zero;

  float4 px[4]; uint4 pw0, pw1;
  auto ldg = [&](int kc) {
    px[0] = *(const float4*)(xp + kc);
    px[1] = *(const float4*)(xp + kc + 4);
    px[2] = *(const float4*)(xp + kc + 8);
    px[3] = *(const float4*)(xp + kc + 12);
    pw0 = *(const uint4*)(wp + kc);
    pw1 = *(const uint4*)(wp + kc + 8);
  };
  ldg(0);

  for (int kc = 0; kc < 512; kc += 32) {
    __syncthreads();
    uint4 xa, xb;
    xa.x = pack2(px[0].x, px[0].y); xa.y = pack2(px[0].z, px[0].w);
    xa.z = pack2(px[1].x, px[1].y); xa.w = pack2(px[1].z, px[1].w);
    xb.x = pack2(px[2].x, px[2].y); xb.y = pack2(px[2].z, px[2].w);
    xb.z = pack2(px[3].x, px[3].y); xb.w = pack2(px[3].z, px[3].w);
    *(uint4*)&Xs[srow][shalf]      = xa;
    *(uint4*)&Xs[srow][shalf + 8]  = xb;
    *(uint4*)&Wsh[srow][shalf]     = pw0;
    *(uint4*)&Wsh[srow][shalf + 8] = pw1;
    __syncthreads();
    if (kc + 32 < 512) ldg(kc + 32);

    short8 xf[4], wf[4];
#pragma unroll
    for (int t = 0; t < 4; ++t) {
      xf[t] = *(const short8*)&Xs[wm + t * 16 + l15][l4 * 8];
      wf[t] = *(const short8*)&Wsh[wn + t * 16 + l15][l4 * 8];
    }
    if (!trans) {
#pragma unroll
      for (int i = 0; i < 4; ++i)
#pragma unroll
        for (int j = 0; j < 4; ++j)
          acc[i][j] = MFMA(wf[i], xf[j], acc[i][j]);   // D[n][m]
    } else {
#pragma unroll
      for (int i = 0; i < 4; ++i)
#pragma unroll
        for (int j = 0; j < 4; ++j)
          acc[i][j] = MFMA(xf[i], wf[j], acc[i][j]);   // D[m][n]
    }
  }

  if (!trans) {
#pragma unroll
    for (int tn = 0; tn < 4; ++tn) {
      float4 b4 = *(const float4*)(bias + n0 + wn + tn * 16 + l4 * 4);
#pragma unroll
      for (int tm = 0; tm < 4; ++tm) {
        uint2 pw;
        pw.x = pack2(acc[tn][tm][0] + b4.x, acc[tn][tm][1] + b4.y);
        pw.y = pack2(acc[tn][tm][2] + b4.z, acc[tn][tm][3] + b4.w);
        *(uint2*)(C + (size_t)(m0 + wm + tm * 16 + l15) * N + n0 + wn + tn * 16 + l4 * 4) = pw;
      }
    }
  } else {
#pragma unroll
    for (int tn = 0; tn < 4; ++tn) {
      float bn = bias[n0 + wn + tn * 16 + l15];
#pragma unroll
      for (int tm = 0; tm < 4; ++tm) {
        uint2 pw;
        pw.x = pack2(acc[tm][tn][0] + bn, acc[tm][tn][1] + bn);
        pw.y = pack2(acc[tm][tn][2] + bn, acc[tm][tn][3] + bn);
        *(uint2*)(C + (size_t)(n0 + wn + tn * 16 + l15) * 2048 + m0 + wm + tm * 16 + l4 * 4) = pw;
      }
    }
  }
}

// Column sums of V (= row sums of V^T [512][2048]) in f32. One wave per row.
__global__ __launch_bounds__(256)
void vsum_kernel(const bf16* __restrict__ Vtg, float* __restrict__ vs)
{
  const int row = blockIdx.x * 4 + (threadIdx.x >> 6);
  const int l = threadIdx.x & 63;
  const bf16* p = Vtg + (size_t)row * 2048 + l * 8;
  float s = 0.f;
#pragma unroll
  for (int c = 0; c < 4; ++c) {
    short8 v = *(const short8*)(p + c * 512);
#pragma unroll
    for (int j = 0; j < 8; ++j) s += b2f((unsigned short)v[j]);
  }
#pragma unroll
  for (int off = 32; off; off >>= 1) s += __shfl_xor(s, off, 64);
  if (l == 0) vs[row] = s;
}

// MFMA fused attention, round-1 shell + wave-n-redistributed scores.
// Round-1 was LDS-throughput-bound (~72% LDS-pipe busy, MfmaUtil 18%): the 4
// waves redundantly read the same K/G1 tiles (each wave = m-slab x all n).
// Now: score phase, wave w owns n-subtile w (16 rows) x ALL 4 m-slabs ->
// K/G LDS reads drop 32 -> 8 per wave-iter. Q/G2 for all 4 slabs live in
// registers (~230 VGPR, launch_bounds(256,2)). P goes through one [64][64]
// swizzled LDS tile (cross-wave), so one extra barrier/iter; PV keeps m-slab
// ownership (unchanged). Denominator: per-lane f32 + cross-wave LDS reduce
// (validated round 2), drops the ones-MFMA.
// Everything else = round 1 verified: n-split 2, Vts staged, XCD remap
// (FETCH 13.4MB), bf16 partials, setprio.
__global__ __launch_bounds__(256, 2)
void attn_mfma_kernel(const bf16* __restrict__ Kb, const bf16* __restrict__ G1b,
                      const bf16* __restrict__ Vtg, const bf16* __restrict__ Qb,
                      const bf16* __restrict__ G2b, bf16* __restrict__ ws)
{
  __shared__ short Ks[64][128];
  __shared__ short G1s[64][128];
  __shared__ short Vts[64][64];
  __shared__ short Ps[64][64];
  __shared__ float Dred[4][64];

  const int tid = threadIdx.x;
  const int w   = tid >> 6;
  const int l   = tid & 63;
  const int l15 = l & 15;
  const int l4  = l >> 4;

  // XCD-aware remap (round-1, verified): grid (32,8,2), f%8 = XCD.
  const int f = blockIdx.x + blockIdx.y * 32 + blockIdx.z * 256;
  const int vid = (f & 7) * 64 + (f >> 3);
  const int m0    = (vid & 31) * 64;
  const int grp   = vid >> 5;
  const int h     = grp & 7;
  const int split = grp >> 3;

  // Q/G2 fragments for ALL 4 m-slabs (wave-n-redistribution needs them all).
  short8 qf[4][4], gf[4][4];
#pragma unroll
  for (int s = 0; s < 4; ++s) {
    const size_t ro = (size_t)(m0 + s * 16 + l15) * 1024 + h * 128 + l4 * 8;
#pragma unroll
    for (int kk = 0; kk < 4; ++kk) {
      qf[s][kk] = *(const short8*)(Qb + ro + kk * 32);
      gf[s][kk] = *(const short8*)(G2b + ro + kk * 32);
    }
  }
  // per-slab scale sc[s] for row m = m0 + s*16 + l15
  float sc[4];
#pragma unroll
  for (int s = 0; s < 4; ++s) {
    float sq = 0.f, sg = 0.f;
#pragma unroll
    for (int kk = 0; kk < 4; ++kk)
#pragma unroll
      for (int j = 0; j < 8; ++j) {
        float q = b2f((unsigned short)qf[s][kk][j]);
        float g = b2f((unsigned short)gf[s][kk][j]);
        sq += q * q; sg += g * g;
      }
    sq += __shfl_xor(sq, 16, 64); sq += __shfl_xor(sq, 32, 64);
    sg += __shfl_xor(sg, 16, 64); sg += __shfl_xor(sg, 32, 64);
    sc[s] = rsqrtf(sq) * rsqrtf(sg) * (1.0f / 16384.0f);
  }

  const int r0  = tid >> 3;
  const int c0  = (tid & 7) * 16;    // shorts
  const int c0b = c0 * 2;            // bytes
  const int jv  = tid >> 2;          // V stage row (dv)
  const int nvB = (tid & 3) * 32;    // V stage col bytes

  short8 pk[4], pg[4], pv0, pv1;
  auto load_tile = [&](int nt) {     // nt in global 64-units
    const int n0 = nt * 64;
    const bf16* kp = Kb  + (size_t)(n0 + r0) * 1024 + h * 128 + c0;
    const bf16* gp = G1b + (size_t)(n0 + r0) * 1024 + h * 128 + c0;
    pk[0] = *(const short8*)(kp);
    pk[1] = *(const short8*)(kp + 8);
    pk[2] = *(const short8*)(kp + 32 * 1024);
    pk[3] = *(const short8*)(kp + 32 * 1024 + 8);
    pg[0] = *(const short8*)(gp);
    pg[1] = *(const short8*)(gp + 8);
    pg[2] = *(const short8*)(gp + 32 * 1024);
    pg[3] = *(const short8*)(gp + 32 * 1024 + 8);
    const bf16* vp = Vtg + (size_t)(h * 64 + jv) * 2048 + n0 + (tid & 3) * 16;
    pv0 = *(const short8*)(vp);
    pv1 = *(const short8*)(vp + 8);
  };
  const int ntbase = split * 16;
  load_tile(ntbase);

  const f32x4 zero = {0.f, 0.f, 0.f, 0.f};
  f32x4 accO[4];
#pragma unroll
  for (int t = 0; t < 4; ++t) accO[t] = zero;
  float dacc[4] = {0.f, 0.f, 0.f, 0.f};

  char* const ksb = (char*)&Ks[0][0];
  char* const g1p = (char*)&G1s[0][0];
  char* const vsb = (char*)&Vts[0][0];
  char* const psb = (char*)&Ps[0][0];

  for (int nt = 0; nt < 16; ++nt) {
    __syncthreads();                       // (1) prev PV done; tiles reusable
    *(short8*)(ksb + KSWZ(r0,      c0b))      = pk[0];
    *(short8*)(ksb + KSWZ(r0,      c0b + 16)) = pk[1];
    *(short8*)(ksb + KSWZ(r0 + 32, c0b))      = pk[2];
    *(short8*)(ksb + KSWZ(r0 + 32, c0b + 16)) = pk[3];
    *(short8*)(g1p + KSWZ(r0,      c0b))      = pg[0];
    *(short8*)(g1p + KSWZ(r0,      c0b + 16)) = pg[1];
    *(short8*)(g1p + KSWZ(r0 + 32, c0b))      = pg[2];
    *(short8*)(g1p + KSWZ(r0 + 32, c0b + 16)) = pg[3];
    *(short8*)(vsb + VSWZ(jv, nvB))           = pv0;
    *(short8*)(vsb + VSWZ(jv, nvB + 16))      = pv1;
    __syncthreads();                       // (2) staged data visible
    if (nt + 1 < 16) load_tile(ntbase + nt + 1);

    // Scores: wave w's n-subtile (K/G rows w*16..w*16+15), all 4 m-slabs.
    // 8 LDS frag reads total (4 kk x {K,G1}), 32 MFMAs.
#pragma unroll
    for (int s = 0; s < 4; ++s) {
      f32x4 sa = zero, sg2 = zero;
      __builtin_amdgcn_s_setprio(1);
#pragma unroll
      for (int kk = 0; kk < 4; ++kk) {
        short8 kbf = *(const short8*)(ksb + KSWZ(w * 16 + l15, kk * 64 + l4 * 16));
        sa  = MFMA(kbf, qf[s][kk], sa);
        short8 gbf = *(const short8*)(g1p + KSWZ(w * 16 + l15, kk * 64 + l4 * 16));
        sg2 = MFMA(gbf, gf[s][kk], sg2);
      }
      __builtin_amdgcn_s_setprio(0);
      // D[n'][m']: n' = l4*4+r (K row w*16+n'), m' = l15 (slab s).
      // P' = exp(x)-1 ~= x + x^2/2 (|x| ~ 1e-4)
      float x0 = sa[0] * sg2[0] * sc[s];
      float x1 = sa[1] * sg2[1] * sc[s];
      float x2 = sa[2] * sg2[2] * sc[s];
      float x3 = sa[3] * sg2[3] * sc[s];
      float p0 = __builtin_fmaf(0.5f * x0, x0, x0);
      float p1 = __builtin_fmaf(0.5f * x1, x1, x1);
      float p2 = __builtin_fmaf(0.5f * x2, x2, x2);
      float p3 = __builtin_fmaf(0.5f * x3, x3, x3);
      dacc[s] += (p0 + p1) + (p2 + p3);    // denominator partial, m = s*16+l15
      uint2 pw;
      pw.x = pack_bf2(p0, p1);
      pw.y = pack_bf2(p2, p3);
      // Ps[m = s*16+l15][n = w*16 + l4*4 .. +3]
      *(uint2*)(psb + PSWZ(s * 16 + l15, w * 32 + l4 * 8)) = pw;
    }
    __syncthreads();                       // (3) full P tile visible

    // PV: wave w owns m-slab w (rows w*16..w*16+15), all n.
#pragma unroll
    for (int ks = 0; ks < 2; ++ks) {
      short8 pf = *(const short8*)(psb + PSWZ(w * 16 + l15, ks * 64 + l4 * 16));
      __builtin_amdgcn_s_setprio(1);
#pragma unroll
      for (int jt = 0; jt < 4; ++jt) {
        short8 vbf = *(const short8*)(vsb + VSWZ(jt * 16 + l15, ks * 64 + l4 * 16));
        accO[jt] = MFMA(pf, vbf, accO[jt]);
      }
      __builtin_amdgcn_s_setprio(0);
    }
  }

  // ---- denominator: reduce lane partials over l4-groups, then across waves ----
#pragma unroll
  for (int s = 0; s < 4; ++s) {
    dacc[s] += __shfl_xor(dacc[s], 16, 64);
    dacc[s] += __shfl_xor(dacc[s], 32, 64);
  }
  __syncthreads();                         // Ps dead; reuse barrier for Dred
  if (l4 == 0) {
#pragma unroll
    for (int s = 0; s < 4; ++s) Dred[w][s * 16 + l15] = dacc[s];
  }
  __syncthreads();

  // ---- write partials ----
  bf16* num = ws + (split ? NUM1_OFF : NUM0_OFF);
  float* den = (float*)(ws + DEN_OFF);
  if (w == 0 && tid < 64) {
    float d = Dred[0][l] + Dred[1][l] + Dred[2][l] + Dred[3][l];
    den[(size_t)(split * 8 + h) * 2048 + m0 + l] = d;
  }
#pragma unroll
  for (int jt = 0; jt < 4; ++jt) {
#pragma unroll
    for (int r = 0; r < 4; ++r)
      num[(size_t)(m0 + w * 16 + l4 * 4 + r) * 512 + h * 64 + jt * 16 + l15]
        = __float2bfloat16(accO[jt][r]);
  }
}

// out[m][c] = (num0+num1+Vsum[c]) / (2048 + den0 + den1), 8 elems/thread
__global__ __launch_bounds__(256)
void combine_kernel(const bf16* __restrict__ ws, float* __restrict__ out)
{
  const unsigned short* num0 = (const unsigned short*)(ws + NUM0_OFF);
  const unsigned short* num1 = (const unsigned short*)(ws + NUM1_OFF);
  const float* den  = (const float*)(ws + DEN_OFF);
  const float* vsum = (const float*)(ws + VSUM_OFF);
  int idx = (blockIdx.x * 256 + threadIdx.x) * 8;
  int m = idx >> 9, c = idx & 511, h = c >> 6;
  float d = 2048.0f + den[(size_t)h * 2048 + m] + den[(size_t)(8 + h) * 2048 + m];
  float rd = 1.0f / d;
  short8 a = *(const short8*)(num0 + idx);
  short8 b = *(const short8*)(num1 + idx);
  float4 v0 = *(const float4*)(vsum + c);
  float4 v1 = *(const float4*)(vsum + c + 4);
  float vs[8] = {v0.x, v0.y, v0.z, v0.w, v1.x, v1.y, v1.z, v1.w};
  float r[8];
#pragma unroll
  for (int j = 0; j < 8; ++j)
    r[j] = (b2f((unsigned short)a[j]) + b2f((unsigned short)b[j]) + vs[j]) * rd;
  *(float4*)(out + idx)     = float4{r[0], r[1], r[2], r[3]};
  *(float4*)(out + idx + 4) = float4{r[4], r[5], r[6], r[7]};
}

extern "C" void kernel_launch(void* const* d_in, const int* in_sizes, int n_in,
                              void* d_out, int out_size, void* d_ws, size_t ws_size,
                              hipStream_t stream) {
  const float* first_app  = (const float*)d_in[0];
  const float* first_pos  = (const float*)d_in[1];
  const float* second_app = (const float*)d_in[2];
  const float* second_pos = (const float*)d_in[3];
  const float* WK  = (const float*)d_in[4];
  const float* bK  = (const float*)d_in[5];
  const float* WQ  = (const float*)d_in[6];
  const float* bQ  = (const float*)d_in[7];
  const float* WV  = (const float*)d_in[8];
  const float* bV  = (const float*)d_in[9];
  const float* WG1 = (const float*)d_in[10];
  const float* bG1 = (const float*)d_in[11];
  const float* WG2 = (const float*)d_in[12];
  const float* bG2 = (const float*)d_in[13];

  bf16* ws = (bf16*)d_ws;

  wtrans_kernel<<<dim3(32, 16, 5), 256, 0, stream>>>(WK, WQ, WG1, WG2, WV, ws);
  proj_mfma_kernel<<<dim3(8, 16, 5), 256, 0, stream>>>(
      first_app, first_pos, second_app, second_pos, bK, bQ, bG1, bG2, bV, ws);
  vsum_kernel<<<dim3(128), 256, 0, stream>>>(ws + VT_OFF, (float*)(ws + VSUM_OFF));
  attn_mfma_kernel<<<dim3(32, 8, 2), 256, 0, stream>>>(
      ws + KB_OFF, ws + G1_OFF, ws + VT_OFF, ws + QB_OFF, ws + G2_OFF, ws);
  combine_kernel<<<dim3(512), 256, 0, stream>>>(ws, (float*)d_out);
}

// Round 6
// 186.875 us; speedup vs baseline: 1.2953x; 1.0060x over previous
//
#include <hip/hip_runtime.h>
#include <hip/hip_bf16.h>

typedef __hip_bfloat16 bf16;
typedef __attribute__((ext_vector_type(8))) short short8;   // 8 bf16 = one MFMA A/B frag
typedef __attribute__((ext_vector_type(4))) float f32x4;    // 16x16 MFMA C/D frag
typedef __attribute__((ext_vector_type(16))) float f32x16;  // 32x32 MFMA C/D frag

#define MFMA(a, b, c)   __builtin_amdgcn_mfma_f32_16x16x32_bf16(a, b, c, 0, 0, 0)
#define MFMA32(a, b, c) __builtin_amdgcn_mfma_f32_32x32x16_bf16(a, b, c, 0, 0, 0)

static __device__ __forceinline__ float b2f(unsigned short u) {
  union { unsigned u; float f; } t; t.u = ((unsigned)u) << 16; return t.f;
}
static __device__ __forceinline__ unsigned short f2bf(float f) {
  union { float f; unsigned u; } t; t.f = f;
  unsigned r = t.u + 0x7fffu + ((t.u >> 16) & 1u);   // RNE
  return (unsigned short)(r >> 16);
}
static __device__ __forceinline__ unsigned pack2(float a, float b) {
  return (unsigned)f2bf(a) | ((unsigned)f2bf(b) << 16);
}
// packed f32x2 -> bf16x2 (RNE); lo -> low 16 bits.
static __device__ __forceinline__ unsigned pack_bf2(float lo, float hi) {
  __hip_bfloat162 h = __float22bfloat162_rn(float2{lo, hi});
  union { __hip_bfloat162 h; unsigned u; } c; c.h = h; return c.u;
}

// ---- workspace layout (bf16 element offsets) ----
#define KB_OFF   ((size_t)0)          // K  [2048][1024]
#define QB_OFF   ((size_t)2097152)    // Q  [2048][1024]
#define G1_OFF   ((size_t)4194304)    // G1 [2048][1024]
#define G2_OFF   ((size_t)6291456)    // G2 [2048][1024]
#define VT_OFF   ((size_t)8388608)    // V^T [512][2048]
#define WT_BASE  ((size_t)9437184)
#define WTK_OFF  (WT_BASE)                       // [1024][512]
#define WTQ_OFF  (WT_BASE + (size_t)524288)
#define WTG1_OFF (WT_BASE + (size_t)1048576)
#define WTG2_OFF (WT_BASE + (size_t)1572864)
#define WTV_OFF  (WT_BASE + (size_t)2097152)     // [512][512]
// After proj, the WT region is dead -> reuse for attention partials:
#define NUM0_OFF (WT_BASE)                       // bf16 [2048][512] (n-split 0)
#define NUM1_OFF (WT_BASE + (size_t)1048576)     // bf16 [2048][512] (n-split 1)
#define DEN_OFF  (WT_BASE + (size_t)2097152)     // f32  [2][8][2048] (as raw bytes)
#define VSUM_OFF (DEN_OFF + (size_t)65536)       // f32  [512] column sums of V

// LDS XOR swizzles (byte-address based, applied identically on write & read)
#define KSWZ(r, cB) ((((r) * 256) + (cB)) ^ ((((r) & 7)) << 4))   // [64][128] bf16 tiles
#define VSWZ(r, cB) ((((r) * 128) + (cB)) ^ ((((r) & 7)) << 4))   // [64][64] bf16 tile

// Transpose + convert W[k][n] fp32 -> Wt[n][k] bf16, all 5 weights in one launch.
__global__ __launch_bounds__(256)
void wtrans_kernel(const float* __restrict__ WK, const float* __restrict__ WQ,
                   const float* __restrict__ WG1, const float* __restrict__ WG2,
                   const float* __restrict__ WV, bf16* __restrict__ ws)
{
  __shared__ float T[32][33];
  const float* W; unsigned short* Wt; int N;
  switch (blockIdx.z) {
    case 0:  W = WK;  Wt = (unsigned short*)(ws + WTK_OFF);  N = 1024; break;
    case 1:  W = WQ;  Wt = (unsigned short*)(ws + WTQ_OFF);  N = 1024; break;
    case 2:  W = WG1; Wt = (unsigned short*)(ws + WTG1_OFF); N = 1024; break;
    case 3:  W = WG2; Wt = (unsigned short*)(ws + WTG2_OFF); N = 1024; break;
    default: W = WV;  Wt = (unsigned short*)(ws + WTV_OFF);  N = 512;  break;
  }
  int n0 = blockIdx.x * 32, k0 = blockIdx.y * 32;
  if (n0 >= N) return;
  int tid = threadIdx.x;
  int kk = tid >> 3, nn = (tid & 7) * 4;
  float4 v = *(const float4*)(W + (size_t)(k0 + kk) * N + n0 + nn);
  T[kk][nn] = v.x; T[kk][nn + 1] = v.y; T[kk][nn + 2] = v.z; T[kk][nn + 3] = v.w;
  __syncthreads();
  int n2 = tid >> 3, k2 = (tid & 7) * 4;
  uint2 pw;
  pw.x = pack2(T[k2][n2],     T[k2 + 1][n2]);
  pw.y = pack2(T[k2 + 2][n2], T[k2 + 3][n2]);
  *(uint2*)(Wt + (size_t)(n0 + n2) * 512 + k0 + k2) = pw;
}

// Batched MFMA projection GEMM (verified round 4).
__global__ __launch_bounds__(256)
void proj_mfma_kernel(const float* __restrict__ fa, const float* __restrict__ fp,
                      const float* __restrict__ sa, const float* __restrict__ sp,
                      const float* __restrict__ bKp, const float* __restrict__ bQp,
                      const float* __restrict__ bG1p, const float* __restrict__ bG2p,
                      const float* __restrict__ bVp, bf16* __restrict__ ws)
{
  __shared__ short Xs[128][40];
  __shared__ short Wsh[128][40];
  const float* X; const unsigned short* Wt; const float* bias; unsigned short* C;
  int N; bool trans = false;
  switch (blockIdx.z) {
    case 0:  X = fa; Wt = (const unsigned short*)(ws + WTK_OFF);  bias = bKp;  C = (unsigned short*)(ws + KB_OFF); N = 1024; break;
    case 1:  X = sa; Wt = (const unsigned short*)(ws + WTQ_OFF);  bias = bQp;  C = (unsigned short*)(ws + QB_OFF); N = 1024; break;
    case 2:  X = fp; Wt = (const unsigned short*)(ws + WTG1_OFF); bias = bG1p; C = (unsigned short*)(ws + G1_OFF); N = 1024; break;
    case 3:  X = sp; Wt = (const unsigned short*)(ws + WTG2_OFF); bias = bG2p; C = (unsigned short*)(ws + G2_OFF); N = 1024; break;
    default: X = fa; Wt = (const unsigned short*)(ws + WTV_OFF);  bias = bVp;  C = (unsigned short*)(ws + VT_OFF); N = 512; trans = true; break;
  }
  const int n0 = blockIdx.x * 128;
  if (n0 >= N) return;
  const int m0 = blockIdx.y * 128;
  const int tid = threadIdx.x;
  const int w = tid >> 6, l = tid & 63, l15 = l & 15, l4 = l >> 4;
  const int wm = (w & 1) * 64, wn = (w >> 1) * 64;
  const int srow = tid >> 1, shalf = (tid & 1) * 16;

  const float* xp = X + (size_t)(m0 + srow) * 512 + shalf;
  const unsigned short* wp = Wt + (size_t)(n0 + srow) * 512 + shalf;

  const f32x4 zero = {0.f, 0.f, 0.f, 0.f};
  f32x4 acc[4][4];
#pragma unroll
  for (int i = 0; i < 4; ++i)
#pragma unroll
    for (int j = 0; j < 4; ++j) acc[i][j] = zero;

  float4 px[4]; uint4 pw0, pw1;
  auto ldg = [&](int kc) {
    px[0] = *(const float4*)(xp + kc);
    px[1] = *(const float4*)(xp + kc + 4);
    px[2] = *(const float4*)(xp + kc + 8);
    px[3] = *(const float4*)(xp + kc + 12);
    pw0 = *(const uint4*)(wp + kc);
    pw1 = *(const uint4*)(wp + kc + 8);
  };
  ldg(0);

  for (int kc = 0; kc < 512; kc += 32) {
    __syncthreads();
    uint4 xa, xb;
    xa.x = pack2(px[0].x, px[0].y); xa.y = pack2(px[0].z, px[0].w);
    xa.z = pack2(px[1].x, px[1].y); xa.w = pack2(px[1].z, px[1].w);
    xb.x = pack2(px[2].x, px[2].y); xb.y = pack2(px[2].z, px[2].w);
    xb.z = pack2(px[3].x, px[3].y); xb.w = pack2(px[3].z, px[3].w);
    *(uint4*)&Xs[srow][shalf]      = xa;
    *(uint4*)&Xs[srow][shalf + 8]  = xb;
    *(uint4*)&Wsh[srow][shalf]     = pw0;
    *(uint4*)&Wsh[srow][shalf + 8] = pw1;
    __syncthreads();
    if (kc + 32 < 512) ldg(kc + 32);

    short8 xf[4], wf[4];
#pragma unroll
    for (int t = 0; t < 4; ++t) {
      xf[t] = *(const short8*)&Xs[wm + t * 16 + l15][l4 * 8];
      wf[t] = *(const short8*)&Wsh[wn + t * 16 + l15][l4 * 8];
    }
    if (!trans) {
#pragma unroll
      for (int i = 0; i < 4; ++i)
#pragma unroll
        for (int j = 0; j < 4; ++j)
          acc[i][j] = MFMA(wf[i], xf[j], acc[i][j]);   // D[n][m]
    } else {
#pragma unroll
      for (int i = 0; i < 4; ++i)
#pragma unroll
        for (int j = 0; j < 4; ++j)
          acc[i][j] = MFMA(xf[i], wf[j], acc[i][j]);   // D[m][n]
    }
  }

  if (!trans) {
#pragma unroll
    for (int tn = 0; tn < 4; ++tn) {
      float4 b4 = *(const float4*)(bias + n0 + wn + tn * 16 + l4 * 4);
#pragma unroll
      for (int tm = 0; tm < 4; ++tm) {
        uint2 pw;
        pw.x = pack2(acc[tn][tm][0] + b4.x, acc[tn][tm][1] + b4.y);
        pw.y = pack2(acc[tn][tm][2] + b4.z, acc[tn][tm][3] + b4.w);
        *(uint2*)(C + (size_t)(m0 + wm + tm * 16 + l15) * N + n0 + wn + tn * 16 + l4 * 4) = pw;
      }
    }
  } else {
#pragma unroll
    for (int tn = 0; tn < 4; ++tn) {
      float bn = bias[n0 + wn + tn * 16 + l15];
#pragma unroll
      for (int tm = 0; tm < 4; ++tm) {
        uint2 pw;
        pw.x = pack2(acc[tm][tn][0] + bn, acc[tm][tn][1] + bn);
        pw.y = pack2(acc[tm][tn][2] + bn, acc[tm][tn][3] + bn);
        *(uint2*)(C + (size_t)(n0 + wn + tn * 16 + l15) * 2048 + m0 + wm + tm * 16 + l4 * 4) = pw;
      }
    }
  }
}

// Column sums of V (= row sums of V^T [512][2048]) in f32. One wave per row.
__global__ __launch_bounds__(256)
void vsum_kernel(const bf16* __restrict__ Vtg, float* __restrict__ vs)
{
  const int row = blockIdx.x * 4 + (threadIdx.x >> 6);
  const int l = threadIdx.x & 63;
  const bf16* p = Vtg + (size_t)row * 2048 + l * 8;
  float s = 0.f;
#pragma unroll
  for (int c = 0; c < 4; ++c) {
    short8 v = *(const short8*)(p + c * 512);
#pragma unroll
    for (int j = 0; j < 8; ++j) s += b2f((unsigned short)v[j]);
  }
#pragma unroll
  for (int off = 32; off; off >>= 1) s += __shfl_xor(s, off, 64);
  if (l == 0) vs[row] = s;
}

// MFMA fused attention, 32x32x16 edition (round-4 design, resubmitted after
// infra failure; source re-audited: no divergent barriers, frag maps verified).
// Evidence: rounds 1/3 show LDS-pipe-bound (~224 LDS ops/block-iter = ~75% of
// 48us; all pipes <25%). 32x32x16 MFMA = 2x MACs/instr at the same 16B/lane
// frag -> score MFMAs 128->64 and score LDS reads 128->64 per block-iter.
// Swapped-operand score D gives each lane col m=l&31 + 16 n-values
// (n' = (reg&3)+8*(reg>>2)+4*hi); cvt_pk pairs + 4x shfl_xor(32) (lane l<->l+32
// share m) rebuild PV A-frags IN REGISTERS -> P never touches LDS. PV partials
// over each wave's n-half; cross-half sum once in epilogue via reused Ks/G1s.
// Denominator: f32 dacc per lane (lane owns one m), ones-MFMA dropped.
// Shell = round 1 verified: n-split 2, Vts staged, XCD remap, prefetch,
// 2 barriers/iter. LDS ops/block-iter 224 -> 152.
__global__ __launch_bounds__(256)
void attn_mfma_kernel(const bf16* __restrict__ Kb, const bf16* __restrict__ G1b,
                      const bf16* __restrict__ Vtg, const bf16* __restrict__ Qb,
                      const bf16* __restrict__ G2b, bf16* __restrict__ ws)
{
  __shared__ short Ks[64][128];
  __shared__ short G1s[64][128];
  __shared__ short Vts[64][64];

  const int tid = threadIdx.x;
  const int w   = tid >> 6;
  const int l   = tid & 63;
  const int l31 = l & 31;
  const int hi  = l >> 5;
  const int wm  = w & 1;     // m-half owner (scores B-operand, PV rows)
  const int wn  = w >> 1;    // n-half owner (scores A-operand, PV k-range)

  // XCD-aware remap (round-1, verified): grid (32,8,2), f%8 = XCD.
  const int f = blockIdx.x + blockIdx.y * 32 + blockIdx.z * 256;
  const int vid = (f & 7) * 64 + (f >> 3);
  const int m0    = (vid & 31) * 64;
  const int grp   = vid >> 5;
  const int h     = grp & 7;
  const int split = grp >> 3;

  // Q/G2 B-frags (32x32x16): lane = col m = wm*32+l31; k = kk*16 + hi*8 + j.
  short8 qf[8], gf[8];
  {
    const size_t ro = (size_t)(m0 + wm * 32 + l31) * 1024 + h * 128 + hi * 8;
#pragma unroll
    for (int kk = 0; kk < 8; ++kk) {
      qf[kk] = *(const short8*)(Qb + ro + kk * 16);
      gf[kk] = *(const short8*)(G2b + ro + kk * 16);
    }
  }
  float sc;
  {
    // lane holds 64 of the row's 128 k-values; partner lane (l^32) has the rest
    float sq = 0.f, sg = 0.f;
#pragma unroll
    for (int kk = 0; kk < 8; ++kk)
#pragma unroll
      for (int j = 0; j < 8; ++j) {
        float q = b2f((unsigned short)qf[kk][j]);
        float g = b2f((unsigned short)gf[kk][j]);
        sq += q * q; sg += g * g;
      }
    sq += __shfl_xor(sq, 32, 64);
    sg += __shfl_xor(sg, 32, 64);
    sc = rsqrtf(sq) * rsqrtf(sg) * (1.0f / 16384.0f);   // per-lane m-row scale
  }

  const int r0  = tid >> 3;
  const int c0  = (tid & 7) * 16;    // shorts
  const int c0b = c0 * 2;            // bytes
  const int jv  = tid >> 2;          // V stage row (dv)
  const int nvB = (tid & 3) * 32;    // V stage col bytes

  short8 pk[4], pg[4], pv0, pv1;
  auto load_tile = [&](int nt) {     // nt in global 64-units
    const int n0 = nt * 64;
    const bf16* kp = Kb  + (size_t)(n0 + r0) * 1024 + h * 128 + c0;
    const bf16* gp = G1b + (size_t)(n0 + r0) * 1024 + h * 128 + c0;
    pk[0] = *(const short8*)(kp);
    pk[1] = *(const short8*)(kp + 8);
    pk[2] = *(const short8*)(kp + 32 * 1024);
    pk[3] = *(const short8*)(kp + 32 * 1024 + 8);
    pg[0] = *(const short8*)(gp);
    pg[1] = *(const short8*)(gp + 8);
    pg[2] = *(const short8*)(gp + 32 * 1024);
    pg[3] = *(const short8*)(gp + 32 * 1024 + 8);
    const bf16* vp = Vtg + (size_t)(h * 64 + jv) * 2048 + n0 + (tid & 3) * 16;
    pv0 = *(const short8*)(vp);
    pv1 = *(const short8*)(vp + 8);
  };
  const int ntbase = split * 16;
  load_tile(ntbase);

  f32x16 accO[2];   // PV partial: rows m (wm-half), cols dv = wo*32+l31
#pragma unroll
  for (int wo = 0; wo < 2; ++wo)
#pragma unroll
    for (int r = 0; r < 16; ++r) accO[wo][r] = 0.f;
  float dacc = 0.f;

  char* const ksb = (char*)&Ks[0][0];
  char* const g1p = (char*)&G1s[0][0];
  char* const vsb = (char*)&Vts[0][0];

  for (int nt = 0; nt < 16; ++nt) {
    __syncthreads();                       // prev iter's reads done
    *(short8*)(ksb + KSWZ(r0,      c0b))      = pk[0];
    *(short8*)(ksb + KSWZ(r0,      c0b + 16)) = pk[1];
    *(short8*)(ksb + KSWZ(r0 + 32, c0b))      = pk[2];
    *(short8*)(ksb + KSWZ(r0 + 32, c0b + 16)) = pk[3];
    *(short8*)(g1p + KSWZ(r0,      c0b))      = pg[0];
    *(short8*)(g1p + KSWZ(r0,      c0b + 16)) = pg[1];
    *(short8*)(g1p + KSWZ(r0 + 32, c0b))      = pg[2];
    *(short8*)(g1p + KSWZ(r0 + 32, c0b + 16)) = pg[3];
    *(short8*)(vsb + VSWZ(jv, nvB))           = pv0;
    *(short8*)(vsb + VSWZ(jv, nvB + 16))      = pv1;
    __syncthreads();                       // staged data visible
    if (nt + 1 < 16) load_tile(ntbase + nt + 1);

    // ---- scores: one 32x32 quadrant per wave (A=K/G1 rows wn-half, B=Q/G2) ----
    f32x16 sa, sg2;
#pragma unroll
    for (int r = 0; r < 16; ++r) { sa[r] = 0.f; sg2[r] = 0.f; }
    __builtin_amdgcn_s_setprio(1);
#pragma unroll
    for (int kk = 0; kk < 8; ++kk) {
      short8 kbf = *(const short8*)(ksb + KSWZ(wn * 32 + l31, kk * 32 + hi * 16));
      sa  = MFMA32(kbf, qf[kk], sa);
      short8 gbf = *(const short8*)(g1p + KSWZ(wn * 32 + l31, kk * 32 + hi * 16));
      sg2 = MFMA32(gbf, gf[kk], sg2);
    }
    __builtin_amdgcn_s_setprio(0);

    // ---- P' = exp(x)-1 ~= x + x^2/2, packed to bf16 pairs in-register ----
    // lane holds col m=l31 (wm-half), rows n' = (reg&3)+8*(reg>>2)+4*hi.
    // c[j] = bf16x2 of n' pair (8*(j>>1) + 4*hi + 2*(j&1) + {0,1}).
    unsigned c[8];
#pragma unroll
    for (int j = 0; j < 8; ++j) {
      float xa = sa[2 * j]     * sg2[2 * j]     * sc;
      float xb = sa[2 * j + 1] * sg2[2 * j + 1] * sc;
      float pa = __builtin_fmaf(0.5f * xa, xa, xa);
      float pb = __builtin_fmaf(0.5f * xb, xb, xb);
      dacc += pa + pb;
      c[j] = pack_bf2(pa, pb);
    }
    // exchange with partner lane (l^32, same m) to build PV A-frags:
    // af0 covers n_local 0..15, af1 covers 16..31 (within this wave's n-half)
    unsigned d0 = (unsigned)__shfl_xor((int)c[0], 32, 64);
    unsigned d1 = (unsigned)__shfl_xor((int)c[1], 32, 64);
    unsigned d2 = (unsigned)__shfl_xor((int)c[2], 32, 64);
    unsigned d3 = (unsigned)__shfl_xor((int)c[3], 32, 64);
    unsigned d4 = (unsigned)__shfl_xor((int)c[4], 32, 64);
    unsigned d5 = (unsigned)__shfl_xor((int)c[5], 32, 64);
    unsigned d6 = (unsigned)__shfl_xor((int)c[6], 32, 64);
    unsigned d7 = (unsigned)__shfl_xor((int)c[7], 32, 64);
    uint4 u0, u1;
    u0.x = hi ? d2 : c[0];  u0.y = hi ? d3 : c[1];
    u0.z = hi ? c[2] : d0;  u0.w = hi ? c[3] : d1;
    u1.x = hi ? d6 : c[4];  u1.y = hi ? d7 : c[5];
    u1.z = hi ? c[6] : d4;  u1.w = hi ? c[7] : d5;
    short8 af0 = *(short8*)&u0;
    short8 af1 = *(short8*)&u1;

    // ---- PV: O_partial[m wm-half][dv 0..63] over this wave's n-half ----
    __builtin_amdgcn_s_setprio(1);
#pragma unroll
    for (int wo = 0; wo < 2; ++wo) {
      short8 vb0 = *(const short8*)(vsb + VSWZ(wo * 32 + l31, wn * 64 + hi * 16));
      accO[wo] = MFMA32(af0, vb0, accO[wo]);
      short8 vb1 = *(const short8*)(vsb + VSWZ(wo * 32 + l31, wn * 64 + 32 + hi * 16));
      accO[wo] = MFMA32(af1, vb1, accO[wo]);
    }
    __builtin_amdgcn_s_setprio(0);
  }

  // ---- epilogue: cross-wn reduction of accO and dacc ----
  dacc += __shfl_xor(dacc, 32, 64);        // partner pair shares m
  __syncthreads();                         // main-loop LDS reads done
  float* scr   = (float*)&Ks[0][0];        // 16 KB scratch (Ks dead)
  float* dredp = (float*)&G1s[0][0];       // 512 B (G1s dead)
  if (l < 32) dredp[w * 32 + l] = dacc;
  if (wn == 1) {
#pragma unroll
    for (int wo = 0; wo < 2; ++wo)
#pragma unroll
      for (int r = 0; r < 16; ++r) {
        int mloc = (r & 3) + 8 * (r >> 2) + 4 * hi;
        scr[((wm * 32 + mloc) * 2 + wo) * 32 + l31] = accO[wo][r];
      }
  }
  __syncthreads();

  bf16* num = ws + (split ? NUM1_OFF : NUM0_OFF);
  float* den = (float*)(ws + DEN_OFF);
  if (wn == 0) {
    if (l < 32)
      den[(size_t)(split * 8 + h) * 2048 + m0 + wm * 32 + l]
        = dredp[w * 32 + l] + dredp[(w + 2) * 32 + l];
#pragma unroll
    for (int wo = 0; wo < 2; ++wo)
#pragma unroll
      for (int r = 0; r < 16; ++r) {
        int mloc = (r & 3) + 8 * (r >> 2) + 4 * hi;
        float v = accO[wo][r] + scr[((wm * 32 + mloc) * 2 + wo) * 32 + l31];
        num[(size_t)(m0 + wm * 32 + mloc) * 512 + h * 64 + wo * 32 + l31]
          = __float2bfloat16(v);
      }
  }
}

// out[m][c] = (num0+num1+Vsum[c]) / (2048 + den0 + den1), 8 elems/thread
__global__ __launch_bounds__(256)
void combine_kernel(const bf16* __restrict__ ws, float* __restrict__ out)
{
  const unsigned short* num0 = (const unsigned short*)(ws + NUM0_OFF);
  const unsigned short* num1 = (const unsigned short*)(ws + NUM1_OFF);
  const float* den  = (const float*)(ws + DEN_OFF);
  const float* vsum = (const float*)(ws + VSUM_OFF);
  int idx = (blockIdx.x * 256 + threadIdx.x) * 8;
  int m = idx >> 9, c = idx & 511, h = c >> 6;
  float d = 2048.0f + den[(size_t)h * 2048 + m] + den[(size_t)(8 + h) * 2048 + m];
  float rd = 1.0f / d;
  short8 a = *(const short8*)(num0 + idx);
  short8 b = *(const short8*)(num1 + idx);
  float4 v0 = *(const float4*)(vsum + c);
  float4 v1 = *(const float4*)(vsum + c + 4);
  float vs[8] = {v0.x, v0.y, v0.z, v0.w, v1.x, v1.y, v1.z, v1.w};
  float r[8];
#pragma unroll
  for (int j = 0; j < 8; ++j)
    r[j] = (b2f((unsigned short)a[j]) + b2f((unsigned short)b[j]) + vs[j]) * rd;
  *(float4*)(out + idx)     = float4{r[0], r[1], r[2], r[3]};
  *(float4*)(out + idx + 4) = float4{r[4], r[5], r[6], r[7]};
}

extern "C" void kernel_launch(void* const* d_in, const int* in_sizes, int n_in,
                              void* d_out, int out_size, void* d_ws, size_t ws_size,
                              hipStream_t stream) {
  const float* first_app  = (const float*)d_in[0];
  const float* first_pos  = (const float*)d_in[1];
  const float* second_app = (const float*)d_in[2];
  const float* second_pos = (const float*)d_in[3];
  const float* WK  = (const float*)d_in[4];
  const float* bK  = (const float*)d_in[5];
  const float* WQ  = (const float*)d_in[6];
  const float* bQ  = (const float*)d_in[7];
  const float* WV  = (const float*)d_in[8];
  const float* bV  = (const float*)d_in[9];
  const float* WG1 = (const float*)d_in[10];
  const float* bG1 = (const float*)d_in[11];
  const float* WG2 = (const float*)d_in[12];
  const float* bG2 = (const float*)d_in[13];

  bf16* ws = (bf16*)d_ws;

  wtrans_kernel<<<dim3(32, 16, 5), 256, 0, stream>>>(WK, WQ, WG1, WG2, WV, ws);
  proj_mfma_kernel<<<dim3(8, 16, 5), 256, 0, stream>>>(
      first_app, first_pos, second_app, second_pos, bK, bQ, bG1, bG2, bV, ws);
  vsum_kernel<<<dim3(128), 256, 0, stream>>>(ws + VT_OFF, (float*)(ws + VSUM_OFF));
  attn_mfma_kernel<<<dim3(32, 8, 2), 256, 0, stream>>>(
      ws + KB_OFF, ws + G1_OFF, ws + VT_OFF, ws + QB_OFF, ws + G2_OFF, ws);
  combine_kernel<<<dim3(512), 256, 0, stream>>>(ws, (float*)d_out);
}

// Round 7
// 176.938 us; speedup vs baseline: 1.3680x; 1.0562x over previous
//
#include <hip/hip_runtime.h>
#include <hip/hip_bf16.h>

typedef __hip_bfloat16 bf16;
typedef __attribute__((ext_vector_type(8))) short short8;   // 8 bf16 = one MFMA A/B frag
typedef __attribute__((ext_vector_type(4))) float f32x4;    // MFMA C/D frag

#define MFMA(a, b, c) __builtin_amdgcn_mfma_f32_16x16x32_bf16(a, b, c, 0, 0, 0)

static __device__ __forceinline__ float b2f(unsigned short u) {
  union { unsigned u; float f; } t; t.u = ((unsigned)u) << 16; return t.f;
}
static __device__ __forceinline__ unsigned short f2bf(float f) {
  union { float f; unsigned u; } t; t.f = f;
  unsigned r = t.u + 0x7fffu + ((t.u >> 16) & 1u);   // RNE
  return (unsigned short)(r >> 16);
}
static __device__ __forceinline__ unsigned pack2(float a, float b) {
  return (unsigned)f2bf(a) | ((unsigned)f2bf(b) << 16);
}
// packed f32x2 -> bf16x2 (RNE); lo -> low 16 bits.
static __device__ __forceinline__ unsigned pack_bf2(float lo, float hi) {
  __hip_bfloat162 h = __float22bfloat162_rn(float2{lo, hi});
  union { __hip_bfloat162 h; unsigned u; } c; c.h = h; return c.u;
}

// ---- workspace layout (bf16 element offsets). d_ws is 256 MiB; we use ~28 MB ----
#define KB_OFF   ((size_t)0)          // K  [2048][1024]
#define QB_OFF   ((size_t)2097152)    // Q  [2048][1024]
#define G1_OFF   ((size_t)4194304)    // G1 [2048][1024]
#define G2_OFF   ((size_t)6291456)    // G2 [2048][1024]
#define VT_OFF   ((size_t)8388608)    // V^T [512][2048]
#define WT_BASE  ((size_t)9437184)
#define WTK_OFF  (WT_BASE)                       // [1024][512]
#define WTQ_OFF  (WT_BASE + (size_t)524288)
#define WTG1_OFF (WT_BASE + (size_t)1048576)
#define WTG2_OFF (WT_BASE + (size_t)1572864)
#define WTV_OFF  (WT_BASE + (size_t)2097152)     // [512][512]
// Attention partials: n-split = 4. NUM0/1 reuse the dead WT region; NUM2/3,
// DEN, VSUM sit above the legacy 23.6MB region (ws is 256 MiB).
#define NUM0_OFF (WT_BASE)                       // bf16 [2048][512] (n-split 0)
#define NUM1_OFF (WT_BASE + (size_t)1048576)     // bf16 [2048][512] (n-split 1)
#define NUM2_OFF ((size_t)11796480)              // bf16 [2048][512] (n-split 2)
#define NUM3_OFF ((size_t)12845056)              // bf16 [2048][512] (n-split 3)
#define DEN_OFF  ((size_t)13893632)              // f32  [4][8][2048] (raw bytes)
#define VSUM_OFF (DEN_OFF + (size_t)131072)      // f32  [512] column sums of V

// LDS XOR swizzles (byte-address based, applied identically on write & read)
#define KSWZ(r, cB) ((((r) * 256) + (cB)) ^ ((((r) & 7)) << 4))   // [64][128] bf16 tiles
#define PSWZ(r, cB) ((((r) * 128) + (cB)) ^ ((((r) & 7)) << 4))   // [16][64] bf16 tile
#define VSWZ(r, cB) ((((r) * 128) + (cB)) ^ ((((r) & 7)) << 4))   // [64][64] bf16 tile

// Transpose + convert W[k][n] fp32 -> Wt[n][k] bf16, all 5 weights in one launch.
__global__ __launch_bounds__(256)
void wtrans_kernel(const float* __restrict__ WK, const float* __restrict__ WQ,
                   const float* __restrict__ WG1, const float* __restrict__ WG2,
                   const float* __restrict__ WV, bf16* __restrict__ ws)
{
  __shared__ float T[32][33];
  const float* W; unsigned short* Wt; int N;
  switch (blockIdx.z) {
    case 0:  W = WK;  Wt = (unsigned short*)(ws + WTK_OFF);  N = 1024; break;
    case 1:  W = WQ;  Wt = (unsigned short*)(ws + WTQ_OFF);  N = 1024; break;
    case 2:  W = WG1; Wt = (unsigned short*)(ws + WTG1_OFF); N = 1024; break;
    case 3:  W = WG2; Wt = (unsigned short*)(ws + WTG2_OFF); N = 1024; break;
    default: W = WV;  Wt = (unsigned short*)(ws + WTV_OFF);  N = 512;  break;
  }
  int n0 = blockIdx.x * 32, k0 = blockIdx.y * 32;
  if (n0 >= N) return;
  int tid = threadIdx.x;
  int kk = tid >> 3, nn = (tid & 7) * 4;
  float4 v = *(const float4*)(W + (size_t)(k0 + kk) * N + n0 + nn);
  T[kk][nn] = v.x; T[kk][nn + 1] = v.y; T[kk][nn + 2] = v.z; T[kk][nn + 3] = v.w;
  __syncthreads();
  int n2 = tid >> 3, k2 = (tid & 7) * 4;
  uint2 pw;
  pw.x = pack2(T[k2][n2],     T[k2 + 1][n2]);
  pw.y = pack2(T[k2 + 2][n2], T[k2 + 3][n2]);
  *(uint2*)(Wt + (size_t)(n0 + n2) * 512 + k0 + k2) = pw;
}

// Batched MFMA projection GEMM (verified round 4).
__global__ __launch_bounds__(256)
void proj_mfma_kernel(const float* __restrict__ fa, const float* __restrict__ fp,
                      const float* __restrict__ sa, const float* __restrict__ sp,
                      const float* __restrict__ bKp, const float* __restrict__ bQp,
                      const float* __restrict__ bG1p, const float* __restrict__ bG2p,
                      const float* __restrict__ bVp, bf16* __restrict__ ws)
{
  __shared__ short Xs[128][40];
  __shared__ short Wsh[128][40];
  const float* X; const unsigned short* Wt; const float* bias; unsigned short* C;
  int N; bool trans = false;
  switch (blockIdx.z) {
    case 0:  X = fa; Wt = (const unsigned short*)(ws + WTK_OFF);  bias = bKp;  C = (unsigned short*)(ws + KB_OFF); N = 1024; break;
    case 1:  X = sa; Wt = (const unsigned short*)(ws + WTQ_OFF);  bias = bQp;  C = (unsigned short*)(ws + QB_OFF); N = 1024; break;
    case 2:  X = fp; Wt = (const unsigned short*)(ws + WTG1_OFF); bias = bG1p; C = (unsigned short*)(ws + G1_OFF); N = 1024; break;
    case 3:  X = sp; Wt = (const unsigned short*)(ws + WTG2_OFF); bias = bG2p; C = (unsigned short*)(ws + G2_OFF); N = 1024; break;
    default: X = fa; Wt = (const unsigned short*)(ws + WTV_OFF);  bias = bVp;  C = (unsigned short*)(ws + VT_OFF); N = 512; trans = true; break;
  }
  const int n0 = blockIdx.x * 128;
  if (n0 >= N) return;
  const int m0 = blockIdx.y * 128;
  const int tid = threadIdx.x;
  const int w = tid >> 6, l = tid & 63, l15 = l & 15, l4 = l >> 4;
  const int wm = (w & 1) * 64, wn = (w >> 1) * 64;
  const int srow = tid >> 1, shalf = (tid & 1) * 16;

  const float* xp = X + (size_t)(m0 + srow) * 512 + shalf;
  const unsigned short* wp = Wt + (size_t)(n0 + srow) * 512 + shalf;

  const f32x4 zero = {0.f, 0.f, 0.f, 0.f};
  f32x4 acc[4][4];
#pragma unroll
  for (int i = 0; i < 4; ++i)
#pragma unroll
    for (int j = 0; j < 4; ++j) acc[i][j] = zero;

  float4 px[4]; uint4 pw0, pw1;
  auto ldg = [&](int kc) {
    px[0] = *(const float4*)(xp + kc);
    px[1] = *(const float4*)(xp + kc + 4);
    px[2] = *(const float4*)(xp + kc + 8);
    px[3] = *(const float4*)(xp + kc + 12);
    pw0 = *(const uint4*)(wp + kc);
    pw1 = *(const uint4*)(wp + kc + 8);
  };
  ldg(0);

  for (int kc = 0; kc < 512; kc += 32) {
    __syncthreads();
    uint4 xa, xb;
    xa.x = pack2(px[0].x, px[0].y); xa.y = pack2(px[0].z, px[0].w);
    xa.z = pack2(px[1].x, px[1].y); xa.w = pack2(px[1].z, px[1].w);
    xb.x = pack2(px[2].x, px[2].y); xb.y = pack2(px[2].z, px[2].w);
    xb.z = pack2(px[3].x, px[3].y); xb.w = pack2(px[3].z, px[3].w);
    *(uint4*)&Xs[srow][shalf]      = xa;
    *(uint4*)&Xs[srow][shalf + 8]  = xb;
    *(uint4*)&Wsh[srow][shalf]     = pw0;
    *(uint4*)&Wsh[srow][shalf + 8] = pw1;
    __syncthreads();
    if (kc + 32 < 512) ldg(kc + 32);

    short8 xf[4], wf[4];
#pragma unroll
    for (int t = 0; t < 4; ++t) {
      xf[t] = *(const short8*)&Xs[wm + t * 16 + l15][l4 * 8];
      wf[t] = *(const short8*)&Wsh[wn + t * 16 + l15][l4 * 8];
    }
    if (!trans) {
#pragma unroll
      for (int i = 0; i < 4; ++i)
#pragma unroll
        for (int j = 0; j < 4; ++j)
          acc[i][j] = MFMA(wf[i], xf[j], acc[i][j]);   // D[n][m]
    } else {
#pragma unroll
      for (int i = 0; i < 4; ++i)
#pragma unroll
        for (int j = 0; j < 4; ++j)
          acc[i][j] = MFMA(xf[i], wf[j], acc[i][j]);   // D[m][n]
    }
  }

  if (!trans) {
#pragma unroll
    for (int tn = 0; tn < 4; ++tn) {
      float4 b4 = *(const float4*)(bias + n0 + wn + tn * 16 + l4 * 4);
#pragma unroll
      for (int tm = 0; tm < 4; ++tm) {
        uint2 pw;
        pw.x = pack2(acc[tn][tm][0] + b4.x, acc[tn][tm][1] + b4.y);
        pw.y = pack2(acc[tn][tm][2] + b4.z, acc[tn][tm][3] + b4.w);
        *(uint2*)(C + (size_t)(m0 + wm + tm * 16 + l15) * N + n0 + wn + tn * 16 + l4 * 4) = pw;
      }
    }
  } else {
#pragma unroll
    for (int tn = 0; tn < 4; ++tn) {
      float bn = bias[n0 + wn + tn * 16 + l15];
#pragma unroll
      for (int tm = 0; tm < 4; ++tm) {
        uint2 pw;
        pw.x = pack2(acc[tm][tn][0] + bn, acc[tm][tn][1] + bn);
        pw.y = pack2(acc[tm][tn][2] + bn, acc[tm][tn][3] + bn);
        *(uint2*)(C + (size_t)(n0 + wn + tn * 16 + l15) * 2048 + m0 + wm + tm * 16 + l4 * 4) = pw;
      }
    }
  }
}

// Column sums of V (= row sums of V^T [512][2048]) in f32. One wave per row.
__global__ __launch_bounds__(256)
void vsum_kernel(const bf16* __restrict__ Vtg, float* __restrict__ vs)
{
  const int row = blockIdx.x * 4 + (threadIdx.x >> 6);
  const int l = threadIdx.x & 63;
  const bf16* p = Vtg + (size_t)row * 2048 + l * 8;
  float s = 0.f;
#pragma unroll
  for (int c = 0; c < 4; ++c) {
    short8 v = *(const short8*)(p + c * 512);
#pragma unroll
    for (int j = 0; j < 8; ++j) s += b2f((unsigned short)v[j]);
  }
#pragma unroll
  for (int off = 32; off; off >>= 1) s += __shfl_xor(s, off, 64);
  if (l == 0) vs[row] = s;
}

// MFMA fused attention = ROUND-1 PROVEN KERNEL (47.9us, best measured),
// with ONLY the n-split changed 2 -> 4 for occupancy.
// Evidence trail: r1/r6 show latency-bound at 2 waves/SIMD (all pipes <25%,
// every structure lands 48-58us). r2 showed occupancy WAS raisable (40%) but
// its +120MB streaming traffic destroyed XCD-L2 residency. This round: 1024
// blocks at unchanged LDS 49152B -> 3 blocks/CU (12 waves/CU, 1.5x r1),
// per-block iters 16 -> 8, added traffic only ~4MB bf16 partials.
// XCD remap (validated r2): each XCD owns one head, ~2.3MB working set <= L2.
__global__ __launch_bounds__(256)
void attn_mfma_kernel(const bf16* __restrict__ Kb, const bf16* __restrict__ G1b,
                      const bf16* __restrict__ Vtg, const bf16* __restrict__ Qb,
                      const bf16* __restrict__ G2b, bf16* __restrict__ ws)
{
  __shared__ short Ks[64][128];
  __shared__ short G1s[64][128];
  __shared__ short Vts[64][64];
  __shared__ short Ps[4][16][64];

  const int tid = threadIdx.x;
  const int w   = tid >> 6;
  const int l   = tid & 63;
  const int l15 = l & 15;
  const int l4  = l >> 4;

  // XCD-aware remap: grid (32,8,4) -> flat f in [0,1024); hw round-robins f%8
  // across XCDs. vid = (f&7)*128 + (f>>3): XCD x gets vids [128x,128x+128) =
  // head x, splits 0..3, all 32 m-tiles.
  const int f = blockIdx.x + blockIdx.y * 32 + blockIdx.z * 256;
  const int vid = (f & 7) * 128 + (f >> 3);
  const int m0    = (vid & 31) * 64;
  const int grp   = vid >> 5;     // 0..31
  const int h     = grp >> 2;
  const int split = grp & 3;

  short8 qf[4], gf[4];
  {
    const size_t ro = (size_t)(m0 + w * 16 + l15) * 1024 + h * 128 + l4 * 8;
#pragma unroll
    for (int kk = 0; kk < 4; ++kk) {
      qf[kk] = *(const short8*)(Qb + ro + kk * 32);
      gf[kk] = *(const short8*)(G2b + ro + kk * 32);
    }
  }
  float sc;
  {
    float sq = 0.f, sg = 0.f;
#pragma unroll
    for (int kk = 0; kk < 4; ++kk)
#pragma unroll
      for (int j = 0; j < 8; ++j) {
        float q = b2f((unsigned short)qf[kk][j]);
        float g = b2f((unsigned short)gf[kk][j]);
        sq += q * q; sg += g * g;
      }
    sq += __shfl_xor(sq, 16, 64); sq += __shfl_xor(sq, 32, 64);
    sg += __shfl_xor(sg, 16, 64); sg += __shfl_xor(sg, 32, 64);
    // per-lane scale for row m = w*16 + l15
    sc = rsqrtf(sq) * rsqrtf(sg) * (1.0f / 16384.0f);
  }

  const int r0  = tid >> 3;
  const int c0  = (tid & 7) * 16;    // shorts
  const int c0b = c0 * 2;            // bytes
  const int jv  = tid >> 2;          // V stage row (dv)
  const int nvB = (tid & 3) * 32;    // V stage col bytes

  short8 pk[4], pg[4], pv0, pv1;
  auto load_tile = [&](int nt) {     // nt in global 64-units
    const int n0 = nt * 64;
    const bf16* kp = Kb  + (size_t)(n0 + r0) * 1024 + h * 128 + c0;
    const bf16* gp = G1b + (size_t)(n0 + r0) * 1024 + h * 128 + c0;
    pk[0] = *(const short8*)(kp);
    pk[1] = *(const short8*)(kp + 8);
    pk[2] = *(const short8*)(kp + 32 * 1024);
    pk[3] = *(const short8*)(kp + 32 * 1024 + 8);
    pg[0] = *(const short8*)(gp);
    pg[1] = *(const short8*)(gp + 8);
    pg[2] = *(const short8*)(gp + 32 * 1024);
    pg[3] = *(const short8*)(gp + 32 * 1024 + 8);
    const bf16* vp = Vtg + (size_t)(h * 64 + jv) * 2048 + n0 + (tid & 3) * 16;
    pv0 = *(const short8*)(vp);
    pv1 = *(const short8*)(vp + 8);
  };
  const int ntbase = split * 8;
  load_tile(ntbase);

  const f32x4 zero = {0.f, 0.f, 0.f, 0.f};
  f32x4 accO[4], accD = zero;
#pragma unroll
  for (int t = 0; t < 4; ++t) accO[t] = zero;

  short8 ones;
#pragma unroll
  for (int j = 0; j < 8; ++j) ones[j] = (short)0x3F80;

  char* const ksb = (char*)&Ks[0][0];
  char* const g1p = (char*)&G1s[0][0];
  char* const vsb = (char*)&Vts[0][0];
  char* const psb = (char*)&Ps[w][0][0];

  for (int nt = 0; nt < 8; ++nt) {
    __syncthreads();
    *(short8*)(ksb + KSWZ(r0,      c0b))      = pk[0];
    *(short8*)(ksb + KSWZ(r0,      c0b + 16)) = pk[1];
    *(short8*)(ksb + KSWZ(r0 + 32, c0b))      = pk[2];
    *(short8*)(ksb + KSWZ(r0 + 32, c0b + 16)) = pk[3];
    *(short8*)(g1p + KSWZ(r0,      c0b))      = pg[0];
    *(short8*)(g1p + KSWZ(r0,      c0b + 16)) = pg[1];
    *(short8*)(g1p + KSWZ(r0 + 32, c0b))      = pg[2];
    *(short8*)(g1p + KSWZ(r0 + 32, c0b + 16)) = pg[3];
    *(short8*)(vsb + VSWZ(jv, nvB))           = pv0;
    *(short8*)(vsb + VSWZ(jv, nvB + 16))      = pv1;
    __syncthreads();
    if (nt + 1 < 8) load_tile(ntbase + nt + 1);

    // scores for this tile: swapped operands -> lane holds S[n-quads][m=l15]
#pragma unroll
    for (int t = 0; t < 4; ++t) {
      f32x4 sa = zero, sg2 = zero;
      __builtin_amdgcn_s_setprio(1);
#pragma unroll
      for (int kk = 0; kk < 4; ++kk) {
        short8 kbf = *(const short8*)(ksb + KSWZ(t * 16 + l15, kk * 64 + l4 * 16));
        sa  = MFMA(kbf, qf[kk], sa);
        short8 gbf = *(const short8*)(g1p + KSWZ(t * 16 + l15, kk * 64 + l4 * 16));
        sg2 = MFMA(gbf, gf[kk], sg2);
      }
      __builtin_amdgcn_s_setprio(0);
      // P' = exp(x)-1 ~= x + x^2/2 (|x| ~ 1e-4)
      float x0 = sa[0] * sg2[0] * sc;
      float x1 = sa[1] * sg2[1] * sc;
      float x2 = sa[2] * sg2[2] * sc;
      float x3 = sa[3] * sg2[3] * sc;
      float p0 = __builtin_fmaf(0.5f * x0, x0, x0);
      float p1 = __builtin_fmaf(0.5f * x1, x1, x1);
      float p2 = __builtin_fmaf(0.5f * x2, x2, x2);
      float p3 = __builtin_fmaf(0.5f * x3, x3, x3);
      uint2 pw;
      pw.x = pack_bf2(p0, p1);
      pw.y = pack_bf2(p2, p3);
      // Ps[m=l15][n = t*16 + l4*4 .. +3]
      *(uint2*)(psb + PSWZ(l15, t * 32 + l4 * 8)) = pw;
    }

    // PV + denominator from swizzled LDS V tile
#pragma unroll
    for (int ks = 0; ks < 2; ++ks) {
      short8 pf = *(const short8*)(psb + PSWZ(l15, ks * 64 + l4 * 16));
      __builtin_amdgcn_s_setprio(1);
      accD = MFMA(pf, ones, accD);
#pragma unroll
      for (int jt = 0; jt < 4; ++jt) {
        short8 vbf = *(const short8*)(vsb + VSWZ(jt * 16 + l15, ks * 64 + l4 * 16));
        accO[jt] = MFMA(pf, vbf, accO[jt]);
      }
      __builtin_amdgcn_s_setprio(0);
    }
  }

  // ---- write partials ----
  size_t noff;
  switch (split) {
    case 0:  noff = NUM0_OFF; break;
    case 1:  noff = NUM1_OFF; break;
    case 2:  noff = NUM2_OFF; break;
    default: noff = NUM3_OFF; break;
  }
  bf16* num = ws + noff;
  float* den = (float*)(ws + DEN_OFF);
  if (l15 == 0) {
#pragma unroll
    for (int r = 0; r < 4; ++r)
      den[(size_t)(split * 8 + h) * 2048 + m0 + w * 16 + l4 * 4 + r] = accD[r];
  }
#pragma unroll
  for (int jt = 0; jt < 4; ++jt) {
#pragma unroll
    for (int r = 0; r < 4; ++r)
      num[(size_t)(m0 + w * 16 + l4 * 4 + r) * 512 + h * 64 + jt * 16 + l15]
        = __float2bfloat16(accO[jt][r]);
  }
}

// out[m][c] = (num0..3 + Vsum[c]) / (2048 + den0..3), 8 elems/thread
__global__ __launch_bounds__(256)
void combine_kernel(const bf16* __restrict__ ws, float* __restrict__ out)
{
  const unsigned short* num0 = (const unsigned short*)(ws + NUM0_OFF);
  const unsigned short* num1 = (const unsigned short*)(ws + NUM1_OFF);
  const unsigned short* num2 = (const unsigned short*)(ws + NUM2_OFF);
  const unsigned short* num3 = (const unsigned short*)(ws + NUM3_OFF);
  const float* den  = (const float*)(ws + DEN_OFF);
  const float* vsum = (const float*)(ws + VSUM_OFF);
  int idx = (blockIdx.x * 256 + threadIdx.x) * 8;
  int m = idx >> 9, c = idx & 511, h = c >> 6;
  float d = 2048.0f + den[(size_t)h * 2048 + m] + den[(size_t)(8 + h) * 2048 + m]
                    + den[(size_t)(16 + h) * 2048 + m] + den[(size_t)(24 + h) * 2048 + m];
  float rd = 1.0f / d;
  short8 a = *(const short8*)(num0 + idx);
  short8 b = *(const short8*)(num1 + idx);
  short8 e = *(const short8*)(num2 + idx);
  short8 g = *(const short8*)(num3 + idx);
  float4 v0 = *(const float4*)(vsum + c);
  float4 v1 = *(const float4*)(vsum + c + 4);
  float vs[8] = {v0.x, v0.y, v0.z, v0.w, v1.x, v1.y, v1.z, v1.w};
  float r[8];
#pragma unroll
  for (int j = 0; j < 8; ++j)
    r[j] = (b2f((unsigned short)a[j]) + b2f((unsigned short)b[j])
          + b2f((unsigned short)e[j]) + b2f((unsigned short)g[j]) + vs[j]) * rd;
  *(float4*)(out + idx)     = float4{r[0], r[1], r[2], r[3]};
  *(float4*)(out + idx + 4) = float4{r[4], r[5], r[6], r[7]};
}

extern "C" void kernel_launch(void* const* d_in, const int* in_sizes, int n_in,
                              void* d_out, int out_size, void* d_ws, size_t ws_size,
                              hipStream_t stream) {
  const float* first_app  = (const float*)d_in[0];
  const float* first_pos  = (const float*)d_in[1];
  const float* second_app = (const float*)d_in[2];
  const float* second_pos = (const float*)d_in[3];
  const float* WK  = (const float*)d_in[4];
  const float* bK  = (const float*)d_in[5];
  const float* WQ  = (const float*)d_in[6];
  const float* bQ  = (const float*)d_in[7];
  const float* WV  = (const float*)d_in[8];
  const float* bV  = (const float*)d_in[9];
  const float* WG1 = (const float*)d_in[10];
  const float* bG1 = (const float*)d_in[11];
  const float* WG2 = (const float*)d_in[12];
  const float* bG2 = (const float*)d_in[13];

  bf16* ws = (bf16*)d_ws;

  wtrans_kernel<<<dim3(32, 16, 5), 256, 0, stream>>>(WK, WQ, WG1, WG2, WV, ws);
  proj_mfma_kernel<<<dim3(8, 16, 5), 256, 0, stream>>>(
      first_app, first_pos, second_app, second_pos, bK, bQ, bG1, bG2, bV, ws);
  vsum_kernel<<<dim3(128), 256, 0, stream>>>(ws + VT_OFF, (float*)(ws + VSUM_OFF));
  attn_mfma_kernel<<<dim3(32, 8, 4), 256, 0, stream>>>(
      ws + KB_OFF, ws + G1_OFF, ws + VT_OFF, ws + QB_OFF, ws + G2_OFF, ws);
  combine_kernel<<<dim3(512), 256, 0, stream>>>(ws, (float*)d_out);
}

// Round 8
// 167.200 us; speedup vs baseline: 1.4477x; 1.0582x over previous
//
#include <hip/hip_runtime.h>
#include <hip/hip_bf16.h>

typedef __hip_bfloat16 bf16;
typedef __attribute__((ext_vector_type(8))) short short8;   // 8 bf16 = one MFMA A/B frag
typedef __attribute__((ext_vector_type(4))) float f32x4;    // MFMA C/D frag

#define MFMA(a, b, c) __builtin_amdgcn_mfma_f32_16x16x32_bf16(a, b, c, 0, 0, 0)

static __device__ __forceinline__ float b2f(unsigned short u) {
  union { unsigned u; float f; } t; t.u = ((unsigned)u) << 16; return t.f;
}
static __device__ __forceinline__ unsigned short f2bf(float f) {
  union { float f; unsigned u; } t; t.f = f;
  unsigned r = t.u + 0x7fffu + ((t.u >> 16) & 1u);   // RNE
  return (unsigned short)(r >> 16);
}
static __device__ __forceinline__ unsigned pack2(float a, float b) {
  return (unsigned)f2bf(a) | ((unsigned)f2bf(b) << 16);
}
// packed f32x2 -> bf16x2 (RNE); lo -> low 16 bits.
static __device__ __forceinline__ unsigned pack_bf2(float lo, float hi) {
  __hip_bfloat162 h = __float22bfloat162_rn(float2{lo, hi});
  union { __hip_bfloat162 h; unsigned u; } c; c.h = h; return c.u;
}

// Direct global->LDS staging (guide m97: width 16). Dest is wave-uniform base +
// lane*16 (rule #21: pre-swizzle the GLOBAL per-lane address, LDS stays linear,
// swizzle on the read side).
#if defined(__has_builtin)
#if __has_builtin(__builtin_amdgcn_global_load_lds)
#define HAVE_GLL 1
#endif
#endif
#ifdef HAVE_GLL
#define LOADLDS(g, p) __builtin_amdgcn_global_load_lds( \
    (const __attribute__((address_space(1))) void*)(g), \
    (__attribute__((address_space(3))) void*)(p), 16, 0, 0)
#else
#define LOADLDS(g, p) do { uint4 t_ = *(const uint4*)(g); \
    *(uint4*)((char*)(p) + (threadIdx.x & 63) * 16) = t_; } while (0)
#endif

// ---- workspace layout (bf16 element offsets). d_ws is 256 MiB; we use ~38 MB ----
#define KB_OFF   ((size_t)0)          // K  [2048][1024]
#define QB_OFF   ((size_t)2097152)    // Q  [2048][1024]
#define G1_OFF   ((size_t)4194304)    // G1 [2048][1024]
#define G2_OFF   ((size_t)6291456)    // G2 [2048][1024]
#define VT_OFF   ((size_t)8388608)    // V^T [512][2048]
#define WT_BASE  ((size_t)9437184)
#define WTK_OFF  (WT_BASE)                       // [1024][512]
#define WTQ_OFF  (WT_BASE + (size_t)524288)
#define WTG1_OFF (WT_BASE + (size_t)1048576)
#define WTG2_OFF (WT_BASE + (size_t)1572864)
#define WTV_OFF  (WT_BASE + (size_t)2097152)     // [512][512]
// After proj, the WT region is dead -> reuse for attention partials:
#define NUM0_OFF (WT_BASE)                       // bf16 [2048][512] (n-split 0)
#define NUM1_OFF (WT_BASE + (size_t)1048576)     // bf16 [2048][512] (n-split 1)
#define NUM2_OFF ((size_t)11796480)              // bf16 [2048][512] (n-split 2)
#define NUM3_OFF ((size_t)12845056)              // bf16 [2048][512] (n-split 3)
#define DEN_OFF  ((size_t)13893632)              // f32  [4][8][2048] (raw bytes)
#define VSUM_OFF (DEN_OFF + (size_t)131072)      // f32  [512] column sums of V
// bf16 copies of the X activations (written by prep, read by proj):
#define XFA_OFF  ((size_t)14680064)              // bf16 [2048][512] first_app
#define XSA_OFF  ((size_t)15728640)              // bf16 [2048][512] second_app
#define XFP_OFF  ((size_t)16777216)              // bf16 [2048][512] first_pos
#define XSP_OFF  ((size_t)17825792)              // bf16 [2048][512] second_pos

// LDS XOR swizzles (byte-address based, applied identically on write & read)
#define KSWZ(r, cB) ((((r) * 256) + (cB)) ^ ((((r) & 7)) << 4))   // [64][128] bf16 tiles
#define PSWZ(r, cB) ((((r) * 128) + (cB)) ^ ((((r) & 7)) << 4))   // [16][64] bf16 tile
#define VSWZ(r, cB) ((((r) * 128) + (cB)) ^ ((((r) & 7)) << 4))   // [64][64] bf16 tile

// prep: z 0-4 = transpose+convert W[k][n] fp32 -> Wt[n][k] bf16 (as before);
//       z 5-8 = convert X activations fp32 -> bf16 (removes the per-k-step
//               pack VALU from proj's K-loop and halves its X fetch bytes).
__global__ __launch_bounds__(256)
void prep_kernel(const float* __restrict__ WK, const float* __restrict__ WQ,
                 const float* __restrict__ WG1, const float* __restrict__ WG2,
                 const float* __restrict__ WV,
                 const float* __restrict__ fa, const float* __restrict__ fp,
                 const float* __restrict__ sa, const float* __restrict__ sp,
                 bf16* __restrict__ ws)
{
  const int z = blockIdx.z;
  const int tid = threadIdx.x;
  if (z >= 5) {  // ---- xconv ----
    const float* src; size_t doff;
    switch (z) {
      case 5:  src = fa; doff = XFA_OFF; break;
      case 6:  src = sa; doff = XSA_OFF; break;
      case 7:  src = fp; doff = XFP_OFF; break;
      default: src = sp; doff = XSP_OFF; break;
    }
    const size_t e = ((size_t)(blockIdx.y * 32 + blockIdx.x) * 256 + tid) * 8;
    float4 a = *(const float4*)(src + e);
    float4 b = *(const float4*)(src + e + 4);
    uint4 o;
    o.x = pack2(a.x, a.y); o.y = pack2(a.z, a.w);
    o.z = pack2(b.x, b.y); o.w = pack2(b.z, b.w);
    *(uint4*)(ws + doff + e) = o;
    return;
  }
  // ---- wtrans ----
  __shared__ float T[32][33];
  const float* W; unsigned short* Wt; int N;
  switch (z) {
    case 0:  W = WK;  Wt = (unsigned short*)(ws + WTK_OFF);  N = 1024; break;
    case 1:  W = WQ;  Wt = (unsigned short*)(ws + WTQ_OFF);  N = 1024; break;
    case 2:  W = WG1; Wt = (unsigned short*)(ws + WTG1_OFF); N = 1024; break;
    case 3:  W = WG2; Wt = (unsigned short*)(ws + WTG2_OFF); N = 1024; break;
    default: W = WV;  Wt = (unsigned short*)(ws + WTV_OFF);  N = 512;  break;
  }
  int n0 = blockIdx.x * 32, k0 = blockIdx.y * 32;
  if (n0 >= N) return;
  int kk = tid >> 3, nn = (tid & 7) * 4;
  float4 v = *(const float4*)(W + (size_t)(k0 + kk) * N + n0 + nn);
  T[kk][nn] = v.x; T[kk][nn + 1] = v.y; T[kk][nn + 2] = v.z; T[kk][nn + 3] = v.w;
  __syncthreads();
  int n2 = tid >> 3, k2 = (tid & 7) * 4;
  uint2 pw;
  pw.x = pack2(T[k2][n2],     T[k2 + 1][n2]);
  pw.y = pack2(T[k2 + 2][n2], T[k2 + 3][n2]);
  *(uint2*)(Wt + (size_t)(n0 + n2) * 512 + k0 + k2) = pw;
}

// Batched MFMA projection GEMM v2 (m97 structure): bf16 inputs both sides,
// BK=64, global_load_lds width-16 staging into linear [128][64] LDS tiles,
// pre-swizzled global source (chunk c' = c ^ (row&7)) + XOR-swizzled
// ds_read_b128 (^((row&7)<<4)) -> conflict-free at 128B row stride.
// Accumulation order and epilogue identical to v1 (bit-identical results).
__global__ __launch_bounds__(256)
void proj_mfma_kernel(const float* __restrict__ bKp, const float* __restrict__ bQp,
                      const float* __restrict__ bG1p, const float* __restrict__ bG2p,
                      const float* __restrict__ bVp, bf16* __restrict__ ws)
{
  __shared__ short As[128][64];
  __shared__ short Bs[128][64];
  const bf16* X; const bf16* Wt; const float* bias; unsigned short* C;
  int N; bool trans = false;
  switch (blockIdx.z) {
    case 0:  X = ws + XFA_OFF; Wt = ws + WTK_OFF;  bias = bKp;  C = (unsigned short*)(ws + KB_OFF); N = 1024; break;
    case 1:  X = ws + XSA_OFF; Wt = ws + WTQ_OFF;  bias = bQp;  C = (unsigned short*)(ws + QB_OFF); N = 1024; break;
    case 2:  X = ws + XFP_OFF; Wt = ws + WTG1_OFF; bias = bG1p; C = (unsigned short*)(ws + G1_OFF); N = 1024; break;
    case 3:  X = ws + XSP_OFF; Wt = ws + WTG2_OFF; bias = bG2p; C = (unsigned short*)(ws + G2_OFF); N = 1024; break;
    default: X = ws + XFA_OFF; Wt = ws + WTV_OFF;  bias = bVp;  C = (unsigned short*)(ws + VT_OFF); N = 512; trans = true; break;
  }
  const int n0 = blockIdx.x * 128;
  if (n0 >= N) return;
  const int m0 = blockIdx.y * 128;
  const int tid = threadIdx.x;
  const int w = tid >> 6, l = tid & 63, l15 = l & 15, l4 = l >> 4;
  const int wm = (w & 1) * 64, wn = (w >> 1) * 64;

  // staging: wave w owns rows [w*32, w*32+32); instr i covers 8 rows (8 lanes x
  // 16B per row). Global chunk pre-swizzled: c' = (l&7) ^ (l>>3).
  const int lr = l >> 3;
  const int cp = (l & 7) ^ lr;
  const bf16* gA = X  + (size_t)(m0 + w * 32 + lr) * 512 + cp * 8;
  const bf16* gB = Wt + (size_t)(n0 + w * 32 + lr) * 512 + cp * 8;
  char* const ldsA = (char*)&As[0][0] + w * 32 * 128;
  char* const ldsB = (char*)&Bs[0][0] + w * 32 * 128;

  const f32x4 zero = {0.f, 0.f, 0.f, 0.f};
  f32x4 acc[4][4];
#pragma unroll
  for (int i = 0; i < 4; ++i)
#pragma unroll
    for (int j = 0; j < 4; ++j) acc[i][j] = zero;

  const int swz = (l15 & 7) << 4;   // read-side XOR (row&7 == l15&7 here)

  for (int kc = 0; kc < 512; kc += 64) {
    __syncthreads();
#pragma unroll
    for (int i = 0; i < 4; ++i) {
      LOADLDS(gA + (size_t)i * 8 * 512 + kc, ldsA + i * 1024);
      LOADLDS(gB + (size_t)i * 8 * 512 + kc, ldsB + i * 1024);
    }
    __syncthreads();

#pragma unroll
    for (int kk = 0; kk < 2; ++kk) {
      short8 xf[4], wf[4];
#pragma unroll
      for (int t = 0; t < 4; ++t) {
        xf[t] = *(const short8*)((char*)&As[0][0] + (wm + t * 16 + l15) * 128
                                  + ((kk * 64 + l4 * 16) ^ swz));
        wf[t] = *(const short8*)((char*)&Bs[0][0] + (wn + t * 16 + l15) * 128
                                  + ((kk * 64 + l4 * 16) ^ swz));
      }
      if (!trans) {
#pragma unroll
        for (int i = 0; i < 4; ++i)
#pragma unroll
          for (int j = 0; j < 4; ++j)
            acc[i][j] = MFMA(wf[i], xf[j], acc[i][j]);   // D[n][m]
      } else {
#pragma unroll
        for (int i = 0; i < 4; ++i)
#pragma unroll
          for (int j = 0; j < 4; ++j)
            acc[i][j] = MFMA(xf[i], wf[j], acc[i][j]);   // D[m][n]
      }
    }
  }

  if (!trans) {
#pragma unroll
    for (int tn = 0; tn < 4; ++tn) {
      float4 b4 = *(const float4*)(bias + n0 + wn + tn * 16 + l4 * 4);
#pragma unroll
      for (int tm = 0; tm < 4; ++tm) {
        uint2 pw;
        pw.x = pack2(acc[tn][tm][0] + b4.x, acc[tn][tm][1] + b4.y);
        pw.y = pack2(acc[tn][tm][2] + b4.z, acc[tn][tm][3] + b4.w);
        *(uint2*)(C + (size_t)(m0 + wm + tm * 16 + l15) * N + n0 + wn + tn * 16 + l4 * 4) = pw;
      }
    }
  } else {
#pragma unroll
    for (int tn = 0; tn < 4; ++tn) {
      float bn = bias[n0 + wn + tn * 16 + l15];
#pragma unroll
      for (int tm = 0; tm < 4; ++tm) {
        uint2 pw;
        pw.x = pack2(acc[tm][tn][0] + bn, acc[tm][tn][1] + bn);
        pw.y = pack2(acc[tm][tn][2] + bn, acc[tm][tn][3] + bn);
        *(uint2*)(C + (size_t)(n0 + wn + tn * 16 + l15) * 2048 + m0 + wm + tm * 16 + l4 * 4) = pw;
      }
    }
  }
}

// Column sums of V (= row sums of V^T [512][2048]) in f32. One wave per row.
__global__ __launch_bounds__(256)
void vsum_kernel(const bf16* __restrict__ Vtg, float* __restrict__ vs)
{
  const int row = blockIdx.x * 4 + (threadIdx.x >> 6);
  const int l = threadIdx.x & 63;
  const bf16* p = Vtg + (size_t)row * 2048 + l * 8;
  float s = 0.f;
#pragma unroll
  for (int c = 0; c < 4; ++c) {
    short8 v = *(const short8*)(p + c * 512);
#pragma unroll
    for (int j = 0; j < 8; ++j) s += b2f((unsigned short)v[j]);
  }
#pragma unroll
  for (int off = 32; off; off >>= 1) s += __shfl_xor(s, off, 64);
  if (l == 0) vs[row] = s;
}

// MFMA fused attention == ROUND-7 KERNEL, UNTOUCHED (48.0us; structural
// latency floor across 4 tried structures). This round attacks proj/prep.
__global__ __launch_bounds__(256)
void attn_mfma_kernel(const bf16* __restrict__ Kb, const bf16* __restrict__ G1b,
                      const bf16* __restrict__ Vtg, const bf16* __restrict__ Qb,
                      const bf16* __restrict__ G2b, bf16* __restrict__ ws)
{
  __shared__ short Ks[64][128];
  __shared__ short G1s[64][128];
  __shared__ short Vts[64][64];
  __shared__ short Ps[4][16][64];

  const int tid = threadIdx.x;
  const int w   = tid >> 6;
  const int l   = tid & 63;
  const int l15 = l & 15;
  const int l4  = l >> 4;

  const int f = blockIdx.x + blockIdx.y * 32 + blockIdx.z * 256;
  const int vid = (f & 7) * 128 + (f >> 3);
  const int m0    = (vid & 31) * 64;
  const int grp   = vid >> 5;     // 0..31
  const int h     = grp >> 2;
  const int split = grp & 3;

  short8 qf[4], gf[4];
  {
    const size_t ro = (size_t)(m0 + w * 16 + l15) * 1024 + h * 128 + l4 * 8;
#pragma unroll
    for (int kk = 0; kk < 4; ++kk) {
      qf[kk] = *(const short8*)(Qb + ro + kk * 32);
      gf[kk] = *(const short8*)(G2b + ro + kk * 32);
    }
  }
  float sc;
  {
    float sq = 0.f, sg = 0.f;
#pragma unroll
    for (int kk = 0; kk < 4; ++kk)
#pragma unroll
      for (int j = 0; j < 8; ++j) {
        float q = b2f((unsigned short)qf[kk][j]);
        float g = b2f((unsigned short)gf[kk][j]);
        sq += q * q; sg += g * g;
      }
    sq += __shfl_xor(sq, 16, 64); sq += __shfl_xor(sq, 32, 64);
    sg += __shfl_xor(sg, 16, 64); sg += __shfl_xor(sg, 32, 64);
    sc = rsqrtf(sq) * rsqrtf(sg) * (1.0f / 16384.0f);
  }

  const int r0  = tid >> 3;
  const int c0  = (tid & 7) * 16;    // shorts
  const int c0b = c0 * 2;            // bytes
  const int jv  = tid >> 2;          // V stage row (dv)
  const int nvB = (tid & 3) * 32;    // V stage col bytes

  short8 pk[4], pg[4], pv0, pv1;
  auto load_tile = [&](int nt) {     // nt in global 64-units
    const int n0 = nt * 64;
    const bf16* kp = Kb  + (size_t)(n0 + r0) * 1024 + h * 128 + c0;
    const bf16* gp = G1b + (size_t)(n0 + r0) * 1024 + h * 128 + c0;
    pk[0] = *(const short8*)(kp);
    pk[1] = *(const short8*)(kp + 8);
    pk[2] = *(const short8*)(kp + 32 * 1024);
    pk[3] = *(const short8*)(kp + 32 * 1024 + 8);
    pg[0] = *(const short8*)(gp);
    pg[1] = *(const short8*)(gp + 8);
    pg[2] = *(const short8*)(gp + 32 * 1024);
    pg[3] = *(const short8*)(gp + 32 * 1024 + 8);
    const bf16* vp = Vtg + (size_t)(h * 64 + jv) * 2048 + n0 + (tid & 3) * 16;
    pv0 = *(const short8*)(vp);
    pv1 = *(const short8*)(vp + 8);
  };
  const int ntbase = split * 8;
  load_tile(ntbase);

  const f32x4 zero = {0.f, 0.f, 0.f, 0.f};
  f32x4 accO[4], accD = zero;
#pragma unroll
  for (int t = 0; t < 4; ++t) accO[t] = zero;

  short8 ones;
#pragma unroll
  for (int j = 0; j < 8; ++j) ones[j] = (short)0x3F80;

  char* const ksb = (char*)&Ks[0][0];
  char* const g1p = (char*)&G1s[0][0];
  char* const vsb = (char*)&Vts[0][0];
  char* const psb = (char*)&Ps[w][0][0];

  for (int nt = 0; nt < 8; ++nt) {
    __syncthreads();
    *(short8*)(ksb + KSWZ(r0,      c0b))      = pk[0];
    *(short8*)(ksb + KSWZ(r0,      c0b + 16)) = pk[1];
    *(short8*)(ksb + KSWZ(r0 + 32, c0b))      = pk[2];
    *(short8*)(ksb + KSWZ(r0 + 32, c0b + 16)) = pk[3];
    *(short8*)(g1p + KSWZ(r0,      c0b))      = pg[0];
    *(short8*)(g1p + KSWZ(r0,      c0b + 16)) = pg[1];
    *(short8*)(g1p + KSWZ(r0 + 32, c0b))      = pg[2];
    *(short8*)(g1p + KSWZ(r0 + 32, c0b + 16)) = pg[3];
    *(short8*)(vsb + VSWZ(jv, nvB))           = pv0;
    *(short8*)(vsb + VSWZ(jv, nvB + 16))      = pv1;
    __syncthreads();
    if (nt + 1 < 8) load_tile(ntbase + nt + 1);

#pragma unroll
    for (int t = 0; t < 4; ++t) {
      f32x4 sa = zero, sg2 = zero;
      __builtin_amdgcn_s_setprio(1);
#pragma unroll
      for (int kk = 0; kk < 4; ++kk) {
        short8 kbf = *(const short8*)(ksb + KSWZ(t * 16 + l15, kk * 64 + l4 * 16));
        sa  = MFMA(kbf, qf[kk], sa);
        short8 gbf = *(const short8*)(g1p + KSWZ(t * 16 + l15, kk * 64 + l4 * 16));
        sg2 = MFMA(gbf, gf[kk], sg2);
      }
      __builtin_amdgcn_s_setprio(0);
      float x0 = sa[0] * sg2[0] * sc;
      float x1 = sa[1] * sg2[1] * sc;
      float x2 = sa[2] * sg2[2] * sc;
      float x3 = sa[3] * sg2[3] * sc;
      float p0 = __builtin_fmaf(0.5f * x0, x0, x0);
      float p1 = __builtin_fmaf(0.5f * x1, x1, x1);
      float p2 = __builtin_fmaf(0.5f * x2, x2, x2);
      float p3 = __builtin_fmaf(0.5f * x3, x3, x3);
      uint2 pw;
      pw.x = pack_bf2(p0, p1);
      pw.y = pack_bf2(p2, p3);
      *(uint2*)(psb + PSWZ(l15, t * 32 + l4 * 8)) = pw;
    }

#pragma unroll
    for (int ks = 0; ks < 2; ++ks) {
      short8 pf = *(const short8*)(psb + PSWZ(l15, ks * 64 + l4 * 16));
      __builtin_amdgcn_s_setprio(1);
      accD = MFMA(pf, ones, accD);
#pragma unroll
      for (int jt = 0; jt < 4; ++jt) {
        short8 vbf = *(const short8*)(vsb + VSWZ(jt * 16 + l15, ks * 64 + l4 * 16));
        accO[jt] = MFMA(pf, vbf, accO[jt]);
      }
      __builtin_amdgcn_s_setprio(0);
    }
  }

  size_t noff;
  switch (split) {
    case 0:  noff = NUM0_OFF; break;
    case 1:  noff = NUM1_OFF; break;
    case 2:  noff = NUM2_OFF; break;
    default: noff = NUM3_OFF; break;
  }
  bf16* num = ws + noff;
  float* den = (float*)(ws + DEN_OFF);
  if (l15 == 0) {
#pragma unroll
    for (int r = 0; r < 4; ++r)
      den[(size_t)(split * 8 + h) * 2048 + m0 + w * 16 + l4 * 4 + r] = accD[r];
  }
#pragma unroll
  for (int jt = 0; jt < 4; ++jt) {
#pragma unroll
    for (int r = 0; r < 4; ++r)
      num[(size_t)(m0 + w * 16 + l4 * 4 + r) * 512 + h * 64 + jt * 16 + l15]
        = __float2bfloat16(accO[jt][r]);
  }
}

// out[m][c] = (num0..3 + Vsum[c]) / (2048 + den0..3), 8 elems/thread
__global__ __launch_bounds__(256)
void combine_kernel(const bf16* __restrict__ ws, float* __restrict__ out)
{
  const unsigned short* num0 = (const unsigned short*)(ws + NUM0_OFF);
  const unsigned short* num1 = (const unsigned short*)(ws + NUM1_OFF);
  const unsigned short* num2 = (const unsigned short*)(ws + NUM2_OFF);
  const unsigned short* num3 = (const unsigned short*)(ws + NUM3_OFF);
  const float* den  = (const float*)(ws + DEN_OFF);
  const float* vsum = (const float*)(ws + VSUM_OFF);
  int idx = (blockIdx.x * 256 + threadIdx.x) * 8;
  int m = idx >> 9, c = idx & 511, h = c >> 6;
  float d = 2048.0f + den[(size_t)h * 2048 + m] + den[(size_t)(8 + h) * 2048 + m]
                    + den[(size_t)(16 + h) * 2048 + m] + den[(size_t)(24 + h) * 2048 + m];
  float rd = 1.0f / d;
  short8 a = *(const short8*)(num0 + idx);
  short8 b = *(const short8*)(num1 + idx);
  short8 e = *(const short8*)(num2 + idx);
  short8 g = *(const short8*)(num3 + idx);
  float4 v0 = *(const float4*)(vsum + c);
  float4 v1 = *(const float4*)(vsum + c + 4);
  float vs[8] = {v0.x, v0.y, v0.z, v0.w, v1.x, v1.y, v1.z, v1.w};
  float r[8];
#pragma unroll
  for (int j = 0; j < 8; ++j)
    r[j] = (b2f((unsigned short)a[j]) + b2f((unsigned short)b[j])
          + b2f((unsigned short)e[j]) + b2f((unsigned short)g[j]) + vs[j]) * rd;
  *(float4*)(out + idx)     = float4{r[0], r[1], r[2], r[3]};
  *(float4*)(out + idx + 4) = float4{r[4], r[5], r[6], r[7]};
}

extern "C" void kernel_launch(void* const* d_in, const int* in_sizes, int n_in,
                              void* d_out, int out_size, void* d_ws, size_t ws_size,
                              hipStream_t stream) {
  const float* first_app  = (const float*)d_in[0];
  const float* first_pos  = (const float*)d_in[1];
  const float* second_app = (const float*)d_in[2];
  const float* second_pos = (const float*)d_in[3];
  const float* WK  = (const float*)d_in[4];
  const float* bK  = (const float*)d_in[5];
  const float* WQ  = (const float*)d_in[6];
  const float* bQ  = (const float*)d_in[7];
  const float* WV  = (const float*)d_in[8];
  const float* bV  = (const float*)d_in[9];
  const float* WG1 = (const float*)d_in[10];
  const float* bG1 = (const float*)d_in[11];
  const float* WG2 = (const float*)d_in[12];
  const float* bG2 = (const float*)d_in[13];

  bf16* ws = (bf16*)d_ws;

  prep_kernel<<<dim3(32, 16, 9), 256, 0, stream>>>(
      WK, WQ, WG1, WG2, WV, first_app, first_pos, second_app, second_pos, ws);
  proj_mfma_kernel<<<dim3(8, 16, 5), 256, 0, stream>>>(bK, bQ, bG1, bG2, bV, ws);
  vsum_kernel<<<dim3(128), 256, 0, stream>>>(ws + VT_OFF, (float*)(ws + VSUM_OFF));
  attn_mfma_kernel<<<dim3(32, 8, 4), 256, 0, stream>>>(
      ws + KB_OFF, ws + G1_OFF, ws + VT_OFF, ws + QB_OFF, ws + G2_OFF, ws);
  combine_kernel<<<dim3(512), 256, 0, stream>>>(ws, (float*)d_out);
}

// Round 9
// 158.412 us; speedup vs baseline: 1.5280x; 1.0555x over previous
//
#include <hip/hip_runtime.h>
#include <hip/hip_bf16.h>

typedef __hip_bfloat16 bf16;
typedef __attribute__((ext_vector_type(8))) short short8;   // 8 bf16 = one MFMA A/B frag
typedef __attribute__((ext_vector_type(4))) float f32x4;    // MFMA C/D frag

#define MFMA(a, b, c) __builtin_amdgcn_mfma_f32_16x16x32_bf16(a, b, c, 0, 0, 0)

static __device__ __forceinline__ float b2f(unsigned short u) {
  union { unsigned u; float f; } t; t.u = ((unsigned)u) << 16; return t.f;
}
static __device__ __forceinline__ unsigned short f2bf(float f) {
  union { float f; unsigned u; } t; t.f = f;
  unsigned r = t.u + 0x7fffu + ((t.u >> 16) & 1u);   // RNE
  return (unsigned short)(r >> 16);
}
static __device__ __forceinline__ unsigned pack2(float a, float b) {
  return (unsigned)f2bf(a) | ((unsigned)f2bf(b) << 16);
}
// packed f32x2 -> bf16x2 (RNE); lo -> low 16 bits.
static __device__ __forceinline__ unsigned pack_bf2(float lo, float hi) {
  __hip_bfloat162 h = __float22bfloat162_rn(float2{lo, hi});
  union { __hip_bfloat162 h; unsigned u; } c; c.h = h; return c.u;
}

// Direct global->LDS staging (guide m97: width 16).
#if defined(__has_builtin)
#if __has_builtin(__builtin_amdgcn_global_load_lds)
#define HAVE_GLL 1
#endif
#endif
#ifdef HAVE_GLL
#define LOADLDS(g, p) __builtin_amdgcn_global_load_lds( \
    (const __attribute__((address_space(1))) void*)(g), \
    (__attribute__((address_space(3))) void*)(p), 16, 0, 0)
#else
#define LOADLDS(g, p) do { uint4 t_ = *(const uint4*)(g); \
    *(uint4*)((char*)(p) + (threadIdx.x & 63) * 16) = t_; } while (0)
#endif

// ---- workspace layout (bf16 element offsets). d_ws is 256 MiB; we use ~38 MB ----
#define KB_OFF   ((size_t)0)          // K  [2048][1024]
#define QB_OFF   ((size_t)2097152)    // Q  [2048][1024]
#define G1_OFF   ((size_t)4194304)    // G1 [2048][1024]
#define G2_OFF   ((size_t)6291456)    // G2 [2048][1024]
#define VT_OFF   ((size_t)8388608)    // V^T [512][2048]
#define WT_BASE  ((size_t)9437184)
#define WTK_OFF  (WT_BASE)                       // [1024][512]
#define WTQ_OFF  (WT_BASE + (size_t)524288)
#define WTG1_OFF (WT_BASE + (size_t)1048576)
#define WTG2_OFF (WT_BASE + (size_t)1572864)
#define WTV_OFF  (WT_BASE + (size_t)2097152)     // [512][512]
// After proj, the WT region is dead -> reuse for attention partials:
#define NUM0_OFF (WT_BASE)                       // bf16 [2048][512] (n-split 0)
#define NUM1_OFF (WT_BASE + (size_t)1048576)     // bf16 [2048][512] (n-split 1)
#define NUM2_OFF ((size_t)11796480)              // bf16 [2048][512] (n-split 2)
#define NUM3_OFF ((size_t)12845056)              // bf16 [2048][512] (n-split 3)
#define DEN_OFF  ((size_t)13893632)              // f32  [4][8][2048] (raw bytes)
#define VSUM_OFF ((size_t)14024704)              // f32  [4][8][64] per-split V col-sums
// bf16 copies of the X activations (written by prep, read by proj):
#define XFA_OFF  ((size_t)14680064)              // bf16 [2048][512] first_app
#define XSA_OFF  ((size_t)15728640)              // bf16 [2048][512] second_app
#define XFP_OFF  ((size_t)16777216)              // bf16 [2048][512] first_pos
#define XSP_OFF  ((size_t)17825792)              // bf16 [2048][512] second_pos

// LDS XOR swizzles (byte-address based, applied identically on write & read)
#define KSWZ(r, cB) ((((r) * 256) + (cB)) ^ ((((r) & 7)) << 4))   // [64][128] bf16 tiles
#define PSWZ(r, cB) ((((r) * 128) + (cB)) ^ ((((r) & 7)) << 4))   // [16][64] bf16 tile
#define VSWZ(r, cB) ((((r) * 128) + (cB)) ^ ((((r) & 7)) << 4))   // [64][64] bf16 tile

// prep: z 0-4 = transpose+convert W fp32 -> Wt bf16; z 5-8 = X fp32 -> bf16.
__global__ __launch_bounds__(256)
void prep_kernel(const float* __restrict__ WK, const float* __restrict__ WQ,
                 const float* __restrict__ WG1, const float* __restrict__ WG2,
                 const float* __restrict__ WV,
                 const float* __restrict__ fa, const float* __restrict__ fp,
                 const float* __restrict__ sa, const float* __restrict__ sp,
                 bf16* __restrict__ ws)
{
  const int z = blockIdx.z;
  const int tid = threadIdx.x;
  if (z >= 5) {  // ---- xconv ----
    const float* src; size_t doff;
    switch (z) {
      case 5:  src = fa; doff = XFA_OFF; break;
      case 6:  src = sa; doff = XSA_OFF; break;
      case 7:  src = fp; doff = XFP_OFF; break;
      default: src = sp; doff = XSP_OFF; break;
    }
    const size_t e = ((size_t)(blockIdx.y * 32 + blockIdx.x) * 256 + tid) * 8;
    float4 a = *(const float4*)(src + e);
    float4 b = *(const float4*)(src + e + 4);
    uint4 o;
    o.x = pack2(a.x, a.y); o.y = pack2(a.z, a.w);
    o.z = pack2(b.x, b.y); o.w = pack2(b.z, b.w);
    *(uint4*)(ws + doff + e) = o;
    return;
  }
  // ---- wtrans ----
  __shared__ float T[32][33];
  const float* W; unsigned short* Wt; int N;
  switch (z) {
    case 0:  W = WK;  Wt = (unsigned short*)(ws + WTK_OFF);  N = 1024; break;
    case 1:  W = WQ;  Wt = (unsigned short*)(ws + WTQ_OFF);  N = 1024; break;
    case 2:  W = WG1; Wt = (unsigned short*)(ws + WTG1_OFF); N = 1024; break;
    case 3:  W = WG2; Wt = (unsigned short*)(ws + WTG2_OFF); N = 1024; break;
    default: W = WV;  Wt = (unsigned short*)(ws + WTV_OFF);  N = 512;  break;
  }
  int n0 = blockIdx.x * 32, k0 = blockIdx.y * 32;
  if (n0 >= N) return;
  int kk = tid >> 3, nn = (tid & 7) * 4;
  float4 v = *(const float4*)(W + (size_t)(k0 + kk) * N + n0 + nn);
  T[kk][nn] = v.x; T[kk][nn + 1] = v.y; T[kk][nn + 2] = v.z; T[kk][nn + 3] = v.w;
  __syncthreads();
  int n2 = tid >> 3, k2 = (tid & 7) * 4;
  uint2 pw;
  pw.x = pack2(T[k2][n2],     T[k2 + 1][n2]);
  pw.y = pack2(T[k2 + 2][n2], T[k2 + 3][n2]);
  *(uint2*)(Wt + (size_t)(n0 + n2) * 512 + k0 + k2) = pw;
}

// Batched MFMA projection GEMM v2 (m97 structure, verified round 8).
__global__ __launch_bounds__(256)
void proj_mfma_kernel(const float* __restrict__ bKp, const float* __restrict__ bQp,
                      const float* __restrict__ bG1p, const float* __restrict__ bG2p,
                      const float* __restrict__ bVp, bf16* __restrict__ ws)
{
  __shared__ short As[128][64];
  __shared__ short Bs[128][64];
  const bf16* X; const bf16* Wt; const float* bias; unsigned short* C;
  int N; bool trans = false;
  switch (blockIdx.z) {
    case 0:  X = ws + XFA_OFF; Wt = ws + WTK_OFF;  bias = bKp;  C = (unsigned short*)(ws + KB_OFF); N = 1024; break;
    case 1:  X = ws + XSA_OFF; Wt = ws + WTQ_OFF;  bias = bQp;  C = (unsigned short*)(ws + QB_OFF); N = 1024; break;
    case 2:  X = ws + XFP_OFF; Wt = ws + WTG1_OFF; bias = bG1p; C = (unsigned short*)(ws + G1_OFF); N = 1024; break;
    case 3:  X = ws + XSP_OFF; Wt = ws + WTG2_OFF; bias = bG2p; C = (unsigned short*)(ws + G2_OFF); N = 1024; break;
    default: X = ws + XFA_OFF; Wt = ws + WTV_OFF;  bias = bVp;  C = (unsigned short*)(ws + VT_OFF); N = 512; trans = true; break;
  }
  const int n0 = blockIdx.x * 128;
  if (n0 >= N) return;
  const int m0 = blockIdx.y * 128;
  const int tid = threadIdx.x;
  const int w = tid >> 6, l = tid & 63, l15 = l & 15, l4 = l >> 4;
  const int wm = (w & 1) * 64, wn = (w >> 1) * 64;

  const int lr = l >> 3;
  const int cp = (l & 7) ^ lr;
  const bf16* gA = X  + (size_t)(m0 + w * 32 + lr) * 512 + cp * 8;
  const bf16* gB = Wt + (size_t)(n0 + w * 32 + lr) * 512 + cp * 8;
  char* const ldsA = (char*)&As[0][0] + w * 32 * 128;
  char* const ldsB = (char*)&Bs[0][0] + w * 32 * 128;

  const f32x4 zero = {0.f, 0.f, 0.f, 0.f};
  f32x4 acc[4][4];
#pragma unroll
  for (int i = 0; i < 4; ++i)
#pragma unroll
    for (int j = 0; j < 4; ++j) acc[i][j] = zero;

  const int swz = (l15 & 7) << 4;   // read-side XOR (row&7 == l15&7 here)

  for (int kc = 0; kc < 512; kc += 64) {
    __syncthreads();
#pragma unroll
    for (int i = 0; i < 4; ++i) {
      LOADLDS(gA + (size_t)i * 8 * 512 + kc, ldsA + i * 1024);
      LOADLDS(gB + (size_t)i * 8 * 512 + kc, ldsB + i * 1024);
    }
    __syncthreads();

#pragma unroll
    for (int kk = 0; kk < 2; ++kk) {
      short8 xf[4], wf[4];
#pragma unroll
      for (int t = 0; t < 4; ++t) {
        xf[t] = *(const short8*)((char*)&As[0][0] + (wm + t * 16 + l15) * 128
                                  + ((kk * 64 + l4 * 16) ^ swz));
        wf[t] = *(const short8*)((char*)&Bs[0][0] + (wn + t * 16 + l15) * 128
                                  + ((kk * 64 + l4 * 16) ^ swz));
      }
      if (!trans) {
#pragma unroll
        for (int i = 0; i < 4; ++i)
#pragma unroll
          for (int j = 0; j < 4; ++j)
            acc[i][j] = MFMA(wf[i], xf[j], acc[i][j]);   // D[n][m]
      } else {
#pragma unroll
        for (int i = 0; i < 4; ++i)
#pragma unroll
          for (int j = 0; j < 4; ++j)
            acc[i][j] = MFMA(xf[i], wf[j], acc[i][j]);   // D[m][n]
      }
    }
  }

  if (!trans) {
#pragma unroll
    for (int tn = 0; tn < 4; ++tn) {
      float4 b4 = *(const float4*)(bias + n0 + wn + tn * 16 + l4 * 4);
#pragma unroll
      for (int tm = 0; tm < 4; ++tm) {
        uint2 pw;
        pw.x = pack2(acc[tn][tm][0] + b4.x, acc[tn][tm][1] + b4.y);
        pw.y = pack2(acc[tn][tm][2] + b4.z, acc[tn][tm][3] + b4.w);
        *(uint2*)(C + (size_t)(m0 + wm + tm * 16 + l15) * N + n0 + wn + tn * 16 + l4 * 4) = pw;
      }
    }
  } else {
#pragma unroll
    for (int tn = 0; tn < 4; ++tn) {
      float bn = bias[n0 + wn + tn * 16 + l15];
#pragma unroll
      for (int tm = 0; tm < 4; ++tm) {
        uint2 pw;
        pw.x = pack2(acc[tm][tn][0] + bn, acc[tm][tn][1] + bn);
        pw.y = pack2(acc[tm][tn][2] + bn, acc[tm][tn][3] + bn);
        *(uint2*)(C + (size_t)(n0 + wn + tn * 16 + l15) * 2048 + m0 + wm + tm * 16 + l4 * 4) = pw;
      }
    }
  }
}

// MFMA fused attention, 8-wave (512-thread) blocks: 2 m-tiles share one staged
// K/G1/V copy -> staging instrs & barriers PER OUTPUT halved; 2 blocks/CU x 8
// waves = 16 waves/CU (was ~12). Per-wave compute (scores -> P -> PV) is
// byte-identical to the round-8 kernel. V column-sum folded in (round-0
// pattern): accumulated during Vts staging, shfl-reduced, written by the
// m0==0 block of each (h,split) -> vsum kernel deleted.
__global__ __launch_bounds__(512)
void attn_mfma_kernel(const bf16* __restrict__ Kb, const bf16* __restrict__ G1b,
                      const bf16* __restrict__ Vtg, const bf16* __restrict__ Qb,
                      const bf16* __restrict__ G2b, bf16* __restrict__ ws)
{
  __shared__ short Ks[64][128];
  __shared__ short G1s[64][128];
  __shared__ short Vts[64][64];
  __shared__ short Ps[8][16][64];

  const int tid = threadIdx.x;
  const int w   = tid >> 6;        // 0..7
  const int wsb = w & 3;           // wave's m-sub within its tile
  const int mt  = w >> 2;          // which of the 2 m-tiles
  const int l   = tid & 63;
  const int l15 = l & 15;
  const int l4  = l >> 4;

  // XCD-aware remap: grid (16,8,4) -> f in [0,512); f%8 = XCD. vid=(f&7)*64+
  // (f>>3): XCD x gets vids [64x,64x+64) = head x, splits 0..3, all 16 m-blocks.
  const int f = blockIdx.x + blockIdx.y * 16 + blockIdx.z * 128;
  const int vid = (f & 7) * 64 + (f >> 3);
  const int m0    = (vid & 15) * 128;
  const int grp   = vid >> 4;      // 0..31
  const int h     = grp >> 2;
  const int split = grp & 3;
  const int mrow0 = m0 + mt * 64;  // this wave-group's 64-row m-tile

  short8 qf[4], gf[4];
  {
    const size_t ro = (size_t)(mrow0 + wsb * 16 + l15) * 1024 + h * 128 + l4 * 8;
#pragma unroll
    for (int kk = 0; kk < 4; ++kk) {
      qf[kk] = *(const short8*)(Qb + ro + kk * 32);
      gf[kk] = *(const short8*)(G2b + ro + kk * 32);
    }
  }
  float sc;
  {
    float sq = 0.f, sg = 0.f;
#pragma unroll
    for (int kk = 0; kk < 4; ++kk)
#pragma unroll
      for (int j = 0; j < 8; ++j) {
        float q = b2f((unsigned short)qf[kk][j]);
        float g = b2f((unsigned short)gf[kk][j]);
        sq += q * q; sg += g * g;
      }
    sq += __shfl_xor(sq, 16, 64); sq += __shfl_xor(sq, 32, 64);
    sg += __shfl_xor(sg, 16, 64); sg += __shfl_xor(sg, 32, 64);
    sc = rsqrtf(sq) * rsqrtf(sg) * (1.0f / 16384.0f);   // per-lane m-row scale
  }

  // staging: 512 threads cover each tile exactly once.
  const int r0  = tid >> 3;          // 0..63  K/G row
  const int c0  = (tid & 7) * 16;    // shorts
  const int c0b = c0 * 2;            // bytes
  const int jv  = tid >> 3;          // 0..63  V row (dv)
  const int nv  = (tid & 7) * 8;     // shorts
  const int nvB = nv * 2;            // bytes

  short8 pk0, pk1, pg0, pg1, pv0;
  auto load_tile = [&](int nt) {     // nt in global 64-units
    const int n0 = nt * 64;
    const bf16* kp = Kb  + (size_t)(n0 + r0) * 1024 + h * 128 + c0;
    const bf16* gp = G1b + (size_t)(n0 + r0) * 1024 + h * 128 + c0;
    pk0 = *(const short8*)(kp);
    pk1 = *(const short8*)(kp + 8);
    pg0 = *(const short8*)(gp);
    pg1 = *(const short8*)(gp + 8);
    const bf16* vp = Vtg + (size_t)(h * 64 + jv) * 2048 + n0 + nv;
    pv0 = *(const short8*)(vp);
  };
  const int ntbase = split * 8;
  load_tile(ntbase);

  const f32x4 zero = {0.f, 0.f, 0.f, 0.f};
  f32x4 accO[4], accD = zero;
#pragma unroll
  for (int t = 0; t < 4; ++t) accO[t] = zero;
  float vsum_part = 0.f;

  short8 ones;
#pragma unroll
  for (int j = 0; j < 8; ++j) ones[j] = (short)0x3F80;

  char* const ksb = (char*)&Ks[0][0];
  char* const g1p = (char*)&G1s[0][0];
  char* const vsb = (char*)&Vts[0][0];
  char* const psb = (char*)&Ps[w][0][0];

  for (int nt = 0; nt < 8; ++nt) {
    __syncthreads();
    *(short8*)(ksb + KSWZ(r0, c0b))      = pk0;
    *(short8*)(ksb + KSWZ(r0, c0b + 16)) = pk1;
    *(short8*)(g1p + KSWZ(r0, c0b))      = pg0;
    *(short8*)(g1p + KSWZ(r0, c0b + 16)) = pg1;
    *(short8*)(vsb + VSWZ(jv, nvB))      = pv0;
#pragma unroll
    for (int j = 0; j < 8; ++j)          // V col-sum partial (this split's n)
      vsum_part += b2f((unsigned short)pv0[j]);
    __syncthreads();
    if (nt + 1 < 8) load_tile(ntbase + nt + 1);

    // scores: swapped operands -> lane holds S[n-quads][m=l15] (wave-private)
#pragma unroll
    for (int t = 0; t < 4; ++t) {
      f32x4 sa = zero, sg2 = zero;
      __builtin_amdgcn_s_setprio(1);
#pragma unroll
      for (int kk = 0; kk < 4; ++kk) {
        short8 kbf = *(const short8*)(ksb + KSWZ(t * 16 + l15, kk * 64 + l4 * 16));
        sa  = MFMA(kbf, qf[kk], sa);
        short8 gbf = *(const short8*)(g1p + KSWZ(t * 16 + l15, kk * 64 + l4 * 16));
        sg2 = MFMA(gbf, gf[kk], sg2);
      }
      __builtin_amdgcn_s_setprio(0);
      // P' = exp(x)-1 ~= x + x^2/2 (|x| ~ 1e-4)
      float x0 = sa[0] * sg2[0] * sc;
      float x1 = sa[1] * sg2[1] * sc;
      float x2 = sa[2] * sg2[2] * sc;
      float x3 = sa[3] * sg2[3] * sc;
      float p0 = __builtin_fmaf(0.5f * x0, x0, x0);
      float p1 = __builtin_fmaf(0.5f * x1, x1, x1);
      float p2 = __builtin_fmaf(0.5f * x2, x2, x2);
      float p3 = __builtin_fmaf(0.5f * x3, x3, x3);
      uint2 pw;
      pw.x = pack_bf2(p0, p1);
      pw.y = pack_bf2(p2, p3);
      *(uint2*)(psb + PSWZ(l15, t * 32 + l4 * 8)) = pw;
    }

    // PV + denominator from swizzled LDS V tile
#pragma unroll
    for (int ks = 0; ks < 2; ++ks) {
      short8 pf = *(const short8*)(psb + PSWZ(l15, ks * 64 + l4 * 16));
      __builtin_amdgcn_s_setprio(1);
      accD = MFMA(pf, ones, accD);
#pragma unroll
      for (int jt = 0; jt < 4; ++jt) {
        short8 vbf = *(const short8*)(vsb + VSWZ(jt * 16 + l15, ks * 64 + l4 * 16));
        accO[jt] = MFMA(pf, vbf, accO[jt]);
      }
      __builtin_amdgcn_s_setprio(0);
    }
  }

  // ---- vsum reduce: 8 consecutive lanes (same jv) hold quarters of row jv ----
  vsum_part += __shfl_xor(vsum_part, 1, 64);
  vsum_part += __shfl_xor(vsum_part, 2, 64);
  vsum_part += __shfl_xor(vsum_part, 4, 64);
  if ((vid & 15) == 0 && (tid & 7) == 0)
    ((float*)(ws + VSUM_OFF))[(size_t)(split * 8 + h) * 64 + jv] = vsum_part;

  // ---- write partials ----
  size_t noff;
  switch (split) {
    case 0:  noff = NUM0_OFF; break;
    case 1:  noff = NUM1_OFF; break;
    case 2:  noff = NUM2_OFF; break;
    default: noff = NUM3_OFF; break;
  }
  bf16* num = ws + noff;
  float* den = (float*)(ws + DEN_OFF);
  if (l15 == 0) {
#pragma unroll
    for (int r = 0; r < 4; ++r)
      den[(size_t)(split * 8 + h) * 2048 + mrow0 + wsb * 16 + l4 * 4 + r] = accD[r];
  }
#pragma unroll
  for (int jt = 0; jt < 4; ++jt) {
#pragma unroll
    for (int r = 0; r < 4; ++r)
      num[(size_t)(mrow0 + wsb * 16 + l4 * 4 + r) * 512 + h * 64 + jt * 16 + l15]
        = __float2bfloat16(accO[jt][r]);
  }
}

// out[m][c] = (num0..3 + Vsum[c]) / (2048 + den0..3), 8 elems/thread
__global__ __launch_bounds__(256)
void combine_kernel(const bf16* __restrict__ ws, float* __restrict__ out)
{
  const unsigned short* num0 = (const unsigned short*)(ws + NUM0_OFF);
  const unsigned short* num1 = (const unsigned short*)(ws + NUM1_OFF);
  const unsigned short* num2 = (const unsigned short*)(ws + NUM2_OFF);
  const unsigned short* num3 = (const unsigned short*)(ws + NUM3_OFF);
  const float* den  = (const float*)(ws + DEN_OFF);
  const float* vsum = (const float*)(ws + VSUM_OFF);   // f32 [4][8][64]
  int idx = (blockIdx.x * 256 + threadIdx.x) * 8;
  int m = idx >> 9, c = idx & 511, h = c >> 6, c64 = c & 63;
  float d = 2048.0f + den[(size_t)h * 2048 + m] + den[(size_t)(8 + h) * 2048 + m]
                    + den[(size_t)(16 + h) * 2048 + m] + den[(size_t)(24 + h) * 2048 + m];
  float rd = 1.0f / d;
  short8 a = *(const short8*)(num0 + idx);
  short8 b = *(const short8*)(num1 + idx);
  short8 e = *(const short8*)(num2 + idx);
  short8 g = *(const short8*)(num3 + idx);
  float vs[8] = {0.f, 0.f, 0.f, 0.f, 0.f, 0.f, 0.f, 0.f};
#pragma unroll
  for (int s = 0; s < 4; ++s) {
    float4 v0 = *(const float4*)(vsum + (size_t)(s * 8 + h) * 64 + c64);
    float4 v1 = *(const float4*)(vsum + (size_t)(s * 8 + h) * 64 + c64 + 4);
    vs[0] += v0.x; vs[1] += v0.y; vs[2] += v0.z; vs[3] += v0.w;
    vs[4] += v1.x; vs[5] += v1.y; vs[6] += v1.z; vs[7] += v1.w;
  }
  float r[8];
#pragma unroll
  for (int j = 0; j < 8; ++j)
    r[j] = (b2f((unsigned short)a[j]) + b2f((unsigned short)b[j])
          + b2f((unsigned short)e[j]) + b2f((unsigned short)g[j]) + vs[j]) * rd;
  *(float4*)(out + idx)     = float4{r[0], r[1], r[2], r[3]};
  *(float4*)(out + idx + 4) = float4{r[4], r[5], r[6], r[7]};
}

extern "C" void kernel_launch(void* const* d_in, const int* in_sizes, int n_in,
                              void* d_out, int out_size, void* d_ws, size_t ws_size,
                              hipStream_t stream) {
  const float* first_app  = (const float*)d_in[0];
  const float* first_pos  = (const float*)d_in[1];
  const float* second_app = (const float*)d_in[2];
  const float* second_pos = (const float*)d_in[3];
  const float* WK  = (const float*)d_in[4];
  const float* bK  = (const float*)d_in[5];
  const float* WQ  = (const float*)d_in[6];
  const float* bQ  = (const float*)d_in[7];
  const float* WV  = (const float*)d_in[8];
  const float* bV  = (const float*)d_in[9];
  const float* WG1 = (const float*)d_in[10];
  const float* bG1 = (const float*)d_in[11];
  const float* WG2 = (const float*)d_in[12];
  const float* bG2 = (const float*)d_in[13];

  bf16* ws = (bf16*)d_ws;

  prep_kernel<<<dim3(32, 16, 9), 256, 0, stream>>>(
      WK, WQ, WG1, WG2, WV, first_app, first_pos, second_app, second_pos, ws);
  proj_mfma_kernel<<<dim3(8, 16, 5), 256, 0, stream>>>(bK, bQ, bG1, bG2, bV, ws);
  attn_mfma_kernel<<<dim3(16, 8, 4), 512, 0, stream>>>(
      ws + KB_OFF, ws + G1_OFF, ws + VT_OFF, ws + QB_OFF, ws + G2_OFF, ws);
  combine_kernel<<<dim3(512), 256, 0, stream>>>(ws, (float*)d_out);
}